// Round 1
// 2685.607 us; speedup vs baseline: 1.0452x; 1.0452x over previous
//
#include <hip/hip_runtime.h>
#include <cstddef>
#include <cstdint>

typedef unsigned short u16;
typedef short bf16x8 __attribute__((ext_vector_type(8)));
typedef float f32x4 __attribute__((ext_vector_type(4)));

__device__ __forceinline__ float gelu_tanh(float x) {
  float x3 = x * x * x;
  float t = tanhf(0.7978845608028654f * (x + 0.044715f * x3));
  return 0.5f * x * (1.0f + t);
}
__device__ __forceinline__ float softplus_f(float x) {
  return (x > 20.0f) ? x : log1pf(expf(x));
}
__device__ __forceinline__ u16 f2bf(float f) {
  uint32_t u = __float_as_uint(f);
  uint32_t r = (u + 0x7fffu + ((u >> 16) & 1u)) >> 16;
  return (u16)r;
}
__device__ __forceinline__ float bf2f(u16 v) {
  return __uint_as_float(((uint32_t)v) << 16);
}

// async global->LDS, 16B/lane; LDS dest = wave-uniform base + lane*16
__device__ __forceinline__ void gload16(const u16* g, u16* l) {
  __builtin_amdgcn_global_load_lds(
      (const __attribute__((address_space(1))) void*)g,
      (__attribute__((address_space(3))) void*)l, 16, 0, 0);
}

// ==================== unified MFMA GEMM, 192x64 tile, two-panel BK=64 ====================
// Tile: 192 rows x 64 cols; 4 waves, wave w owns rows [w*48, w*48+48) x all 64 cols.
// Grid: (M/192, N/64) -> always an exact multiple of 256 blocks for our shapes
// (M=12288 -> 64 row-blocks; N=768 -> 12, N=1536 -> 24, N=1024 -> 16).
// A [M][K] bf16 row-major; Bt [N][K] bf16.
// MODE 0: Cf = v              MODE 1: Cb = bf16(gelu(v))
// MODE 2: Cf += v             MODE 3: decoder scatter out = v + bias
// MODE 4: Cf += v + bf2f(Db)  MODE 5: Cf += v; Cb = bf16(Cf)
// MODE 6: Cb = bf16(v)
template <int TN, int MODE>
__global__ __launch_bounds__(256) void gemm_kernel(
    const u16* __restrict__ A, const u16* __restrict__ Bt, int K, int ldc,
    float* __restrict__ Cf, u16* __restrict__ Cb,
    const float* __restrict__ bias, const u16* __restrict__ Db) {
  static_assert(TN == 64, "192x64 tile only");
  __shared__ u16 As[2][192 * 32];
  __shared__ u16 Bs[2][64 * 32];
  const int m0 = blockIdx.x * 192, n0 = blockIdx.y * 64;
  const int tid = threadIdx.x;
  const int lane = tid & 63, w = tid >> 6;
  const int lane15 = lane & 15, quad = lane >> 4;
  const int r0 = lane >> 2, e0 = (lane & 3) * 8;

  // A: wave w stages its own 48 rows as 3 segments of 16 rows each
  const u16* ag0 = A + (size_t)(m0 + w * 48 + r0) * K + e0;
  const u16* ag1 = ag0 + (size_t)16 * K;
  const u16* ag2 = ag0 + (size_t)32 * K;
  // B: wave w stages rows [n0 + w*16, n0 + w*16 + 16)
  const u16* bg0 = Bt + (size_t)(n0 + w * 16 + r0) * K + e0;

  f32x4 acc[3][4] = {};
  const int abase = (w * 48 + lane15) * 32 + quad * 8;
  const int bbase = lane15 * 32 + quad * 8;

  for (int k0 = 0; k0 < K; k0 += 64) {
#pragma unroll
    for (int p = 0; p < 2; ++p) {
      const int kk = k0 + 32 * p;
      gload16(ag0 + kk, &As[p][(w * 48) * 32]);
      gload16(ag1 + kk, &As[p][(w * 48 + 16) * 32]);
      gload16(ag2 + kk, &As[p][(w * 48 + 32) * 32]);
      gload16(bg0 + kk, &Bs[p][(w * 16) * 32]);
    }
    __syncthreads();
#pragma unroll
    for (int p = 0; p < 2; ++p) {
      bf16x8 af[3], bf[4];
#pragma unroll
      for (int i = 0; i < 3; ++i) af[i] = *(const bf16x8*)&As[p][abase + i * 16 * 32];
#pragma unroll
      for (int j = 0; j < 4; ++j) bf[j] = *(const bf16x8*)&Bs[p][bbase + j * 16 * 32];
#pragma unroll
      for (int i = 0; i < 3; ++i)
#pragma unroll
        for (int j = 0; j < 4; ++j)
          acc[i][j] = __builtin_amdgcn_mfma_f32_16x16x32_bf16(af[i], bf[j], acc[i][j], 0, 0, 0);
    }
    __syncthreads();
  }

  const int mw = m0 + w * 48;
#pragma unroll
  for (int i = 0; i < 3; ++i) {
#pragma unroll
    for (int j = 0; j < 4; ++j) {
      const int col = n0 + j * 16 + lane15;
#pragma unroll
      for (int r = 0; r < 4; ++r) {
        const int row = mw + i * 16 + quad * 4 + r;
        const float v = acc[i][j][r];
        const size_t idx = (size_t)row * ldc + col;
        if (MODE == 0) {
          Cf[idx] = v;
        } else if (MODE == 1) {
          Cb[idx] = f2bf(gelu_tanh(v));
        } else if (MODE == 2) {
          Cf[idx] += v;
        } else if (MODE == 3) {
          const int frame = row >> 8, pix = row & 255;
          const int hp = pix >> 4, wp = pix & 15;
          const int co = col >> 8, p1 = (col >> 4) & 15, p2 = col & 15;
          Cf[(((size_t)frame * 4 + co) * 256 + hp * 16 + p1) * 256 + wp * 16 + p2] = v + bias[col];
        } else if (MODE == 4) {
          Cf[idx] += v + bf2f(Db[idx]);
        } else if (MODE == 5) {
          const float nz = Cf[idx] + v;
          Cf[idx] = nz;
          Cb[idx] = f2bf(nz);
        } else if (MODE == 6) {
          Cb[idx] = f2bf(v);
        }
      }
    }
  }
}

// ==================== conv3x3 implicit-GEMM, 192x64 tile, two-panel BK=64 ====================
// grid (64,12) = 768 blocks = exactly 3 blocks/CU (was (96,6)=576 -> 2.25/CU imbalance)
__global__ __launch_bounds__(256) void conv_mfma_kernel(
    const u16* __restrict__ xnp, const u16* __restrict__ Btc,
    const float* __restrict__ cbias,
    float* __restrict__ z, u16* __restrict__ zb) {
  __shared__ u16 As[2][192 * 32];
  __shared__ u16 Bs[2][64 * 32];
  const int m0 = blockIdx.x * 192, n0 = blockIdx.y * 64;
  const int tid = threadIdx.x;
  const int lane = tid & 63, w = tid >> 6;
  const int lane15 = lane & 15, quad = lane >> 4;
  const int r0 = lane >> 2, e0 = (lane & 3) * 8;

  // halo-mapped A row offsets, one per 16-row segment owned by this wave
  const int rowA0 = m0 + w * 48 + r0;
  long long cen[3];
#pragma unroll
  for (int s = 0; s < 3; ++s) {
    const int rA = rowA0 + 16 * s;
    cen[s] = ((long long)(rA >> 8) * 324 + ((((rA & 255) >> 4) + 1) * 18) + (rA & 15) + 1) * 768 + e0;
  }
  const u16* bg = Btc + (size_t)(n0 + w * 16 + r0) * 6912 + e0;

  f32x4 acc[3][4] = {};
  const int abase = (w * 48 + lane15) * 32 + quad * 8;
  const int bbase = lane15 * 32 + quad * 8;

  for (int tap = 0; tap < 9; ++tap) {
    const int doff = ((tap / 3 - 1) * 18 + (tap % 3 - 1)) * 768;
    const u16* a0 = xnp + cen[0] + doff;
    const u16* a1 = xnp + cen[1] + doff;
    const u16* a2 = xnp + cen[2] + doff;
    const u16* b0 = bg + tap * 768;
    for (int kc = 0; kc < 768; kc += 64) {
#pragma unroll
      for (int p = 0; p < 2; ++p) {
        const int kk = kc + 32 * p;
        gload16(a0 + kk, &As[p][(w * 48) * 32]);
        gload16(a1 + kk, &As[p][(w * 48 + 16) * 32]);
        gload16(a2 + kk, &As[p][(w * 48 + 32) * 32]);
        gload16(b0 + kk, &Bs[p][(w * 16) * 32]);
      }
      __syncthreads();
#pragma unroll
      for (int p = 0; p < 2; ++p) {
        bf16x8 af[3], bf[4];
#pragma unroll
        for (int i = 0; i < 3; ++i) af[i] = *(const bf16x8*)&As[p][abase + i * 16 * 32];
#pragma unroll
        for (int j = 0; j < 4; ++j) bf[j] = *(const bf16x8*)&Bs[p][bbase + j * 16 * 32];
#pragma unroll
        for (int i = 0; i < 3; ++i)
#pragma unroll
          for (int j = 0; j < 4; ++j)
            acc[i][j] = __builtin_amdgcn_mfma_f32_16x16x32_bf16(af[i], bf[j], acc[i][j], 0, 0, 0);
      }
      __syncthreads();
    }
  }

  const int mw = m0 + w * 48;
#pragma unroll
  for (int i = 0; i < 3; ++i) {
#pragma unroll
    for (int j = 0; j < 4; ++j) {
      const int col = n0 + j * 16 + lane15;
      const float bv = cbias[col];
#pragma unroll
      for (int r = 0; r < 4; ++r) {
        const int row = mw + i * 16 + quad * 4 + r;
        const size_t idx = (size_t)row * 768 + col;
        const float nz = z[idx] + acc[i][j][r] + bv;
        z[idx] = nz;
        zb[idx] = f2bf(nz);
      }
    }
  }
}

// ==================== encoder: patch-embed MFMA (fp32->bf16 staging, runs once) ====================
__global__ __launch_bounds__(256) void encoder_mfma_kernel(
    const float* __restrict__ x, const float* __restrict__ ew,
    const float* __restrict__ eb, float* __restrict__ z) {
  __shared__ u16 As[128 * 32];
  __shared__ u16 Bs[128 * 32];
  const int m0 = blockIdx.x * 128, n0 = blockIdx.y * 128;
  const int tid = threadIdx.x;
  const int lane = tid & 63, w = tid >> 6;
  const int lane15 = lane & 15, quad = lane >> 4;
  const int srow = tid >> 1, half = tid & 1;
  const int arow = m0 + srow;
  const int frame = arow >> 8, pix = arow & 255, hh = pix >> 4, ww = pix & 15;

  f32x4 acc[4][4] = {};
  const int wy = w >> 1, wx = w & 1;
  const int ar_base = (wy * 64 + lane15) * 32 + quad * 8;
  const int br_base = (wx * 64 + lane15) * 32 + quad * 8;

  for (int k0 = 0; k0 < 1024; k0 += 32) {
    const int gk = k0 + half * 16;
    const int c = gk >> 8, ph = (gk >> 4) & 15;
    const float* ax = x + (((size_t)(frame * 4 + c) * 256 + hh * 16 + ph) * 256 + ww * 16);
    const float* bx = ew + (size_t)(n0 + srow) * 1024 + gk;
    u16 ta[16], tb[16];
#pragma unroll
    for (int j = 0; j < 4; ++j) {
      const float4 va = *(const float4*)(ax + j * 4);
      const float4 vb = *(const float4*)(bx + j * 4);
      ta[j * 4 + 0] = f2bf(va.x); ta[j * 4 + 1] = f2bf(va.y);
      ta[j * 4 + 2] = f2bf(va.z); ta[j * 4 + 3] = f2bf(va.w);
      tb[j * 4 + 0] = f2bf(vb.x); tb[j * 4 + 1] = f2bf(vb.y);
      tb[j * 4 + 2] = f2bf(vb.z); tb[j * 4 + 3] = f2bf(vb.w);
    }
    __syncthreads();
    *(uint4*)&As[srow * 32 + half * 16] = *(uint4*)ta;
    *(uint4*)&As[srow * 32 + half * 16 + 8] = *(uint4*)(ta + 8);
    *(uint4*)&Bs[srow * 32 + half * 16] = *(uint4*)tb;
    *(uint4*)&Bs[srow * 32 + half * 16 + 8] = *(uint4*)(tb + 8);
    __syncthreads();
    bf16x8 af[4], bfv[4];
#pragma unroll
    for (int i = 0; i < 4; ++i) af[i] = *(const bf16x8*)&As[ar_base + i * 16 * 32];
#pragma unroll
    for (int j = 0; j < 4; ++j) bfv[j] = *(const bf16x8*)&Bs[br_base + j * 16 * 32];
#pragma unroll
    for (int i = 0; i < 4; ++i)
#pragma unroll
      for (int j = 0; j < 4; ++j)
        acc[i][j] = __builtin_amdgcn_mfma_f32_16x16x32_bf16(af[i], bfv[j], acc[i][j], 0, 0, 0);
  }

  const int mw = m0 + wy * 64, nw = n0 + wx * 64;
#pragma unroll
  for (int i = 0; i < 4; ++i)
#pragma unroll
    for (int j = 0; j < 4; ++j) {
      const int col = nw + j * 16 + lane15;
      const float bv = eb[col];
#pragma unroll
      for (int r = 0; r < 4; ++r) {
        const int row = mw + i * 16 + quad * 4 + r;
        z[(size_t)row * 768 + col] = acc[i][j][r] + bv;
      }
    }
}

// ==================== weight prep ====================
__global__ __launch_bounds__(256) void expand_kernel(
    const float* __restrict__ Wre, const float* __restrict__ Wim,
    int ldw, int Kc, int Nc, u16* __restrict__ Wt) {
  __shared__ float tile[32][33];
  const int k0 = blockIdx.x * 32, n0 = blockIdx.y * 32;
  const bool khi = k0 >= Kc, nhi = n0 >= Nc;
  const float* src = (khi != nhi) ? Wim : Wre;
  const float sgn = (!nhi && khi) ? -1.0f : 1.0f;
  const int sk = k0 - (khi ? Kc : 0), sn = n0 - (nhi ? Nc : 0);
  const int c = threadIdx.x & 31, r8 = threadIdx.x >> 5;
  for (int r = r8; r < 32; r += 8)
    tile[r][c] = src[(size_t)(sk + r) * ldw + sn + c];
  __syncthreads();
  const int twoK = 2 * Kc;
  for (int r = r8; r < 32; r += 8)
    Wt[(size_t)(n0 + r) * twoK + k0 + c] = f2bf(sgn * tile[c][r]);
}

__global__ __launch_bounds__(256) void reorder_cw_kernel(
    const float* __restrict__ cwl, u16* __restrict__ Btc) {
  __shared__ float buf[6912];
  const int o = blockIdx.x;
  const float* src = cwl + (size_t)o * 6912;
  for (int i = threadIdx.x; i < 6912; i += 256) buf[i] = src[i];
  __syncthreads();
  u16* dst = Btc + (size_t)o * 6912;
  for (int i = threadIdx.x; i < 6912; i += 256) {
    const int tap = i / 768, cc = i - tap * 768;
    dst[i] = f2bf(buf[cc * 9 + tap]);
  }
}

__global__ __launch_bounds__(256) void cast_bf16_kernel(
    const float* __restrict__ in, u16* __restrict__ out, int n) {
  const int g = blockIdx.x * 256 + threadIdx.x;
  if (g < n) out[g] = f2bf(in[g]);
}

// ==================== LayerNorm fp32-in (halo writer) ====================
__global__ __launch_bounds__(192) void ln_kernel(
    const float* __restrict__ in, const float* __restrict__ g,
    const float* __restrict__ b, u16* __restrict__ out) {
  const int row = blockIdx.x, tid = threadIdx.x;
  const float4 v = *(const float4*)(in + (size_t)row * 768 + tid * 4);
  float s = v.x + v.y + v.z + v.w;
  float q = v.x * v.x + v.y * v.y + v.z * v.z + v.w * v.w;
#pragma unroll
  for (int off = 32; off > 0; off >>= 1) {
    s += __shfl_down(s, off);
    q += __shfl_down(q, off);
  }
  __shared__ float rs[3], rq[3];
  if ((tid & 63) == 0) { rs[tid >> 6] = s; rq[tid >> 6] = q; }
  __syncthreads();
  const float S = rs[0] + rs[1] + rs[2], Q = rq[0] + rq[1] + rq[2];
  const float mean = S * (1.0f / 768.0f);
  const float inv = rsqrtf(Q * (1.0f / 768.0f) - mean * mean + 1e-5f);
  const float4 gv = *(const float4*)(g + tid * 4);
  const float4 bv = *(const float4*)(b + tid * 4);
  u16 p[4];
  p[0] = f2bf((v.x - mean) * inv * gv.x + bv.x);
  p[1] = f2bf((v.y - mean) * inv * gv.y + bv.y);
  p[2] = f2bf((v.z - mean) * inv * gv.z + bv.z);
  p[3] = f2bf((v.w - mean) * inv * gv.w + bv.w);
  const int f = row >> 8, pp = row & 255, h = pp >> 4, ww = pp & 15;
  const size_t base = ((size_t)f * 324 + (h + 1) * 18 + ww + 1) * 768;
  *(uint2*)(out + base + tid * 4) = *(uint2*)p;
}

// ==================== LayerNorm bf16-in (flat writer) ====================
__global__ __launch_bounds__(192) void ln_bf_kernel(
    const u16* __restrict__ in, const float* __restrict__ g,
    const float* __restrict__ b, u16* __restrict__ out) {
  const int row = blockIdx.x, tid = threadIdx.x;
  const uint2 raw = *(const uint2*)(in + (size_t)row * 768 + tid * 4);
  const u16* rp = (const u16*)&raw;
  const float v0 = bf2f(rp[0]), v1 = bf2f(rp[1]), v2 = bf2f(rp[2]), v3 = bf2f(rp[3]);
  float s = v0 + v1 + v2 + v3;
  float q = v0 * v0 + v1 * v1 + v2 * v2 + v3 * v3;
#pragma unroll
  for (int off = 32; off > 0; off >>= 1) {
    s += __shfl_down(s, off);
    q += __shfl_down(q, off);
  }
  __shared__ float rs[3], rq[3];
  if ((tid & 63) == 0) { rs[tid >> 6] = s; rq[tid >> 6] = q; }
  __syncthreads();
  const float S = rs[0] + rs[1] + rs[2], Q = rq[0] + rq[1] + rq[2];
  const float mean = S * (1.0f / 768.0f);
  const float inv = rsqrtf(Q * (1.0f / 768.0f) - mean * mean + 1e-5f);
  const float4 gv = *(const float4*)(g + tid * 4);
  const float4 bv = *(const float4*)(b + tid * 4);
  u16 p[4];
  p[0] = f2bf((v0 - mean) * inv * gv.x + bv.x);
  p[1] = f2bf((v1 - mean) * inv * gv.y + bv.y);
  p[2] = f2bf((v2 - mean) * inv * gv.z + bv.z);
  p[3] = f2bf((v3 - mean) * inv * gv.w + bv.w);
  *(uint2*)(out + (size_t)row * 768 + tid * 4) = *(uint2*)p;
}

// ==================== mean over 256 pixels (bf16 in) ====================
__global__ __launch_bounds__(768) void mean_kernel(
    const u16* __restrict__ eig, float* __restrict__ mr, float* __restrict__ mi) {
  const int f = blockIdx.x, c = threadIdx.x;
  const u16* p = eig + (size_t)f * 256 * 768 + c;
  float s0 = 0.f, s1 = 0.f, s2 = 0.f, s3 = 0.f;
  for (int px = 0; px < 256; px += 4) {
    s0 += bf2f(p[(size_t)px * 768]);
    s1 += bf2f(p[(size_t)(px + 1) * 768]);
    s2 += bf2f(p[(size_t)(px + 2) * 768]);
    s3 += bf2f(p[(size_t)(px + 3) * 768]);
  }
  const float tot = (s0 + s1 + s2 + s3) * (1.0f / 256.0f);
  if (c < 384) mr[f * 384 + c] = tot;
  else         mi[f * 384 + c - 384] = tot;
}

// ==================== flux scan + operator precompute ====================
__global__ __launch_bounds__(384) void flux_kernel(
    const float* __restrict__ dt, const float* __restrict__ lamf,
    const float* __restrict__ nu, const float* __restrict__ omega,
    const float* __restrict__ mr, const float* __restrict__ mi,
    float* __restrict__ fluxr, float* __restrict__ fluxi,
    float* __restrict__ opdr, float* __restrict__ opdi,
    float* __restrict__ opfr, float* __restrict__ opfi) {
  const int b = blockIdx.x;
  const int d = threadIdx.x;
  const float sp = softplus_f(lamf[d]);
  float lre = -softplus_f(nu[d]);
  lre = fmaxf(lre, -5.0f);
  const float lim = omega[d];
  const float den = lre * lre + lim * lim;
  float fr = 0.f, fi = 0.f;
  for (int t = 0; t < 12; ++t) {
    const float dtv = dt[b * 12 + t];
    const int idx = (b * 12 + t) * 384 + d;
    const float A = expf(-sp * dtv);
    fr = A * fr + mr[idx] * dtv;
    fi = A * fi + mi[idx] * dtv;
    fluxr[idx] = fr; fluxi[idx] = fi;
    const float ed = expf(lre * dtv);
    const float odr = ed * cosf(lim * dtv);
    const float odi = ed * sinf(lim * dtv);
    opdr[idx] = odr; opdi[idx] = odi;
    const float nr_ = odr - 1.0f, ni_ = odi;
    opfr[idx] = (nr_ * lre + ni_ * lim) / den;
    opfi[idx] = (ni_ * lre - nr_ * lim) / den;
  }
}

// ==================== small fp32 complex GEMM + gate-product epilogue ====================
#define SBM 64
#define SBN 64
#define SBK 32
__global__ __launch_bounds__(256) void cgemm_src_kernel(
    const float* __restrict__ Ar, const float* __restrict__ Ai, int lda,
    const float* __restrict__ Wr, const float* __restrict__ Wi, int ldw,
    const float* __restrict__ Wg,
    float* __restrict__ G, float* __restrict__ SGr, float* __restrict__ SGi,
    int ldc, int M, int K) {
  __shared__ float Asr[SBK][SBM], Asi[SBK][SBM];
  __shared__ float Wsr[SBK][SBN], Wsi[SBK][SBN];
  const int m0 = blockIdx.x * SBM;
  const int n0 = blockIdx.y * SBN;
  const int tid = threadIdx.x;
  const int tn = tid & 15, tm = tid >> 4;
  float accr[4][4] = {}, acci[4][4] = {};
  for (int k0 = 0; k0 < K; k0 += SBK) {
    for (int s = tid; s < 512; s += 256) {
      {
        int r = s >> 3, kk = (s & 7) << 2;
        int row = m0 + r;
        float4 vr = {0.f, 0.f, 0.f, 0.f}, vi = {0.f, 0.f, 0.f, 0.f};
        if (row < M) {
          vr = *(const float4*)(Ar + (size_t)row * lda + k0 + kk);
          vi = *(const float4*)(Ai + (size_t)row * lda + k0 + kk);
        }
        Asr[kk + 0][r] = vr.x; Asr[kk + 1][r] = vr.y; Asr[kk + 2][r] = vr.z; Asr[kk + 3][r] = vr.w;
        Asi[kk + 0][r] = vi.x; Asi[kk + 1][r] = vi.y; Asi[kk + 2][r] = vi.z; Asi[kk + 3][r] = vi.w;
      }
      {
        int wr_ = s >> 4, wc = (s & 15) << 2;
        *(float4*)&Wsr[wr_][wc] = *(const float4*)(Wr + (size_t)(k0 + wr_) * ldw + n0 + wc);
        *(float4*)&Wsi[wr_][wc] = *(const float4*)(Wi + (size_t)(k0 + wr_) * ldw + n0 + wc);
      }
    }
    __syncthreads();
#pragma unroll
    for (int kk = 0; kk < SBK; ++kk) {
      float4 ar4 = *(const float4*)&Asr[kk][tm << 2];
      float4 ai4 = *(const float4*)&Asi[kk][tm << 2];
      float4 wr4 = *(const float4*)&Wsr[kk][tn << 2];
      float4 wi4 = *(const float4*)&Wsi[kk][tn << 2];
      float ar[4] = {ar4.x, ar4.y, ar4.z, ar4.w};
      float ai[4] = {ai4.x, ai4.y, ai4.z, ai4.w};
      float wr[4] = {wr4.x, wr4.y, wr4.z, wr4.w};
      float wi[4] = {wi4.x, wi4.y, wi4.z, wi4.w};
#pragma unroll
      for (int i = 0; i < 4; ++i)
#pragma unroll
        for (int j = 0; j < 4; ++j) {
          accr[i][j] = fmaf(ar[i], wr[j], accr[i][j]);
          accr[i][j] = fmaf(-ai[i], wi[j], accr[i][j]);
          acci[i][j] = fmaf(ar[i], wi[j], acci[i][j]);
          acci[i][j] = fmaf(ai[i], wr[j], acci[i][j]);
        }
    }
    __syncthreads();
  }
#pragma unroll
  for (int i = 0; i < 4; ++i) {
    int row = m0 + (tm << 2) + i;
    if (row >= M) continue;
#pragma unroll
    for (int j = 0; j < 4; ++j) {
      int col = n0 + (tn << 2) + j;
      size_t idx = (size_t)row * ldc + col;
      const float gate = 1.0f / (1.0f + expf(-Ar[idx] * Wg[col]));
      G[idx] = gate;
      SGr[idx] = accr[i][j] * (1.0f - gate);
      SGi[idx] = acci[i][j] * (1.0f - gate);
    }
  }
}

// ==================== fused forcing + u_out pscan (bf16 in) -> bf16 ub ====================
__global__ __launch_bounds__(256) void pscan_fused_kernel(
    const u16* __restrict__ eig,
    const float* __restrict__ Gv,
    const float* __restrict__ SGr, const float* __restrict__ SGi,
    const float* __restrict__ opfr, const float* __restrict__ opfi,
    const float* __restrict__ opdr, const float* __restrict__ opdi,
    u16* __restrict__ ub) {
  const int g = blockIdx.x * 256 + threadIdx.x;
  if (g >= 4 * 256 * 384) return;
  const int d = g % 384;
  const int pix = (g / 384) & 255;
  const int b = g / (384 * 256);
  float ur = 0.f, ui = 0.f;
  for (int t = 0; t < 12; ++t) {
    const int frame = b * 12 + t;
    const size_t idx = ((size_t)frame * 256 + pix) * 768 + d;
    const int fidx = frame * 384 + d;
    const float G = Gv[fidx];
    const float fr = bf2f(eig[idx]) * G + SGr[fidx];
    const float fi = bf2f(eig[idx + 384]) * G + SGi[fidx];
    const float pr = opfr[fidx], pi = opfi[fidx];
    const float utr = fr * pr - fi * pi;
    const float uti = fr * pi + fi * pr;
    const float ar = opdr[fidx], ai = opdi[fidx];
    const float nr = ar * ur - ai * ui + utr;
    const float ni = ar * ui + ai * ur + uti;
    ub[idx] = f2bf(nr); ub[idx + 384] = f2bf(ni);
    ur = nr; ui = ni;
  }
}

extern "C" void kernel_launch(void* const* d_in, const int* in_sizes, int n_in,
                              void* d_out, int out_size, void* d_ws, size_t ws_size,
                              hipStream_t stream) {
  const float* x        = (const float*)d_in[0];
  const float* dt       = (const float*)d_in[1];
  const float* enc_w    = (const float*)d_in[2];
  const float* enc_b    = (const float*)d_in[3];
  const float* ns_g     = (const float*)d_in[4];
  const float* ns_b     = (const float*)d_in[5];
  const float* cw       = (const float*)d_in[6];
  const float* cb       = (const float*)d_in[7];
  const float* nt_g     = (const float*)d_in[8];
  const float* nt_b     = (const float*)d_in[9];
  const float* E_re     = (const float*)d_in[10];
  const float* E_im     = (const float*)d_in[11];
  const float* Ei_re    = (const float*)d_in[12];
  const float* Ei_im    = (const float*)d_in[13];
  const float* lam_flux = (const float*)d_in[14];
  const float* Ws_re    = (const float*)d_in[15];
  const float* Ws_im    = (const float*)d_in[16];
  const float* Wg       = (const float*)d_in[17];
  const float* nu       = (const float*)d_in[18];
  const float* omega    = (const float*)d_in[19];
  const float* w1_re    = (const float*)d_in[20];
  const float* w1_im    = (const float*)d_in[21];
  const float* w2_re    = (const float*)d_in[22];
  const float* w2_im    = (const float*)d_in[23];
  const float* dec_w    = (const float*)d_in[24];
  const float* dec_b    = (const float*)d_in[25];
  float* out = (float*)d_out;

  const size_t NPF = 12288ull * 768;        // 9,437,184
  const size_t XNP = 48ull * 324 * 768;     // halo-padded plane
  const size_t SM = 48ull * 384;

  float* z    = (float*)d_ws;                // [12288][768] fp32 residual master
  float* eigf = z + NPF;                     // region A (NPF floats)
  float* dff  = eigf + NPF;                  // region B (NPF floats)
  u16* xnp    = (u16*)(dff + NPF);           // halo xnbp / flat xnb / ub
  u16* Btc    = xnp + XNP;                   // [768][6912]
  u16* Et     = Btc + 5308416;               // [768][768]
  u16* Eit    = Et + 589824;
  u16* W1t    = Eit + 589824;                // 2 chunks x [1536][768]
  u16* W2t    = W1t + 2359296;               // 2 chunks x [768][1536]
  u16* dwt    = W2t + 2359296;               // [1024][768]
  float* sm   = (float*)(dwt + 786432);
  float* mr    = sm;            float* mi    = mr + SM;
  float* fluxr = mi + SM;       float* fluxi = fluxr + SM;
  float* opdr  = fluxi + SM;    float* opdi  = opdr + SM;
  float* opfr  = opdi + SM;     float* opfi  = opfr + SM;
  float* Gv    = opfi + SM;     float* SGr   = Gv + SM;
  float* SGi   = SGr + SM;

  const size_t need = ((char*)(SGi + SM)) - ((char*)d_ws);
  if (ws_size < need) return;

  // region A: eig_b (bf16, first half) / h1b (bf16 FFN chunk, full region; disjoint lifetime)
  u16* eig_b = (u16*)eigf;
  u16* h1b   = (u16*)eigf;
  // region B: df_b (bf16, first half) + zbuf (bf16, second half)
  u16* df_b  = (u16*)dff;
  u16* zbuf  = (u16*)dff + NPF;

  cast_bf16_kernel<<<(786432 + 255) / 256, 256, 0, stream>>>(dec_w, dwt, 786432);
  encoder_mfma_kernel<<<dim3(96, 6), 256, 0, stream>>>(x, enc_w, enc_b, z);

  for (int l = 0; l < 4; ++l) {
    const size_t DD = 384ull * 384, DF = 384ull * 1536;
    hipMemsetAsync(xnp, 0, XNP * sizeof(u16), stream);  // zero halo borders
    reorder_cw_kernel<<<768, 256, 0, stream>>>(cw + (size_t)l * 768 * 768 * 9, Btc);
    expand_kernel<<<dim3(24, 24), 256, 0, stream>>>(E_re + l * DD, E_im + l * DD, 384, 384, 384, Et);
    expand_kernel<<<dim3(24, 24), 256, 0, stream>>>(Ei_re + l * DD, Ei_im + l * DD, 384, 384, 384, Eit);
    for (int ch = 0; ch < 2; ++ch) {
      expand_kernel<<<dim3(24, 48), 256, 0, stream>>>(
          w1_re + l * DF + ch * 768, w1_im + l * DF + ch * 768, 1536, 384, 768, W1t + (size_t)ch * 1179648);
      expand_kernel<<<dim3(48, 24), 256, 0, stream>>>(
          w2_re + l * DF + (size_t)ch * 768 * 384, w2_im + l * DF + (size_t)ch * 768 * 384, 384, 768, 384,
          W2t + (size_t)ch * 1179648);
    }

    ln_kernel<<<12288, 192, 0, stream>>>(z, ns_g + l * 768, ns_b + l * 768, xnp);
    conv_mfma_kernel<<<dim3(64, 12), 256, 0, stream>>>(xnp, Btc, cb + l * 768, z, zbuf);
    gemm_kernel<64, 6><<<dim3(64, 12), 256, 0, stream>>>(zbuf, Et, 768, 768, nullptr, eig_b, nullptr, nullptr);
    mean_kernel<<<48, 768, 0, stream>>>(eig_b, mr, mi);
    flux_kernel<<<4, 384, 0, stream>>>(dt, lam_flux + l * 384, nu + l * 384, omega + l * 384,
                                       mr, mi, fluxr, fluxi, opdr, opdi, opfr, opfi);
    cgemm_src_kernel<<<dim3(1, 6), 256, 0, stream>>>(
        fluxr, fluxi, 384, Ws_re + l * DD, Ws_im + l * DD, 384,
        Wg + l * 384, Gv, SGr, SGi, 384, 48, 384);
    pscan_fused_kernel<<<1536, 256, 0, stream>>>(eig_b, Gv, SGr, SGi, opfr, opfi, opdr, opdi, xnp);
    gemm_kernel<64, 6><<<dim3(64, 12), 256, 0, stream>>>(xnp, Eit, 768, 768, nullptr, df_b, nullptr, nullptr);
    ln_bf_kernel<<<12288, 192, 0, stream>>>(df_b, nt_g + l * 768, nt_b + l * 768, xnp);
    for (int ch = 0; ch < 2; ++ch) {
      gemm_kernel<64, 1><<<dim3(64, 24), 256, 0, stream>>>(
          xnp, W1t + (size_t)ch * 1179648, 768, 1536, nullptr, h1b, nullptr, nullptr);
      if (ch == 0) {
        // z += W2 + df (df-residual fused, bf16 df read)
        gemm_kernel<64, 4><<<dim3(64, 12), 256, 0, stream>>>(
            h1b, W2t, 1536, 768, z, nullptr, nullptr, df_b);
      } else if (l < 3) {
        gemm_kernel<64, 2><<<dim3(64, 12), 256, 0, stream>>>(
            h1b, W2t + 1179648, 1536, 768, z, nullptr, nullptr, nullptr);
      } else {
        // final layer: also emit zbuf for the decoder
        gemm_kernel<64, 5><<<dim3(64, 12), 256, 0, stream>>>(
            h1b, W2t + 1179648, 1536, 768, z, zbuf, nullptr, nullptr);
      }
    }
  }

  gemm_kernel<64, 3><<<dim3(64, 16), 256, 0, stream>>>(zbuf, dwt, 768, 0, out, nullptr, dec_b, nullptr);
}

// Round 2
// 2511.737 us; speedup vs baseline: 1.1175x; 1.0692x over previous
//
#include <hip/hip_runtime.h>
#include <cstddef>
#include <cstdint>

typedef unsigned short u16;
typedef short bf16x8 __attribute__((ext_vector_type(8)));
typedef float f32x4 __attribute__((ext_vector_type(4)));

__device__ __forceinline__ float gelu_tanh(float x) {
  float x3 = x * x * x;
  float t = tanhf(0.7978845608028654f * (x + 0.044715f * x3));
  return 0.5f * x * (1.0f + t);
}
__device__ __forceinline__ float softplus_f(float x) {
  return (x > 20.0f) ? x : log1pf(expf(x));
}
__device__ __forceinline__ u16 f2bf(float f) {
  uint32_t u = __float_as_uint(f);
  uint32_t r = (u + 0x7fffu + ((u >> 16) & 1u)) >> 16;
  return (u16)r;
}
__device__ __forceinline__ float bf2f(u16 v) {
  return __uint_as_float(((uint32_t)v) << 16);
}

// async global->LDS, 16B/lane; LDS dest = wave-uniform base + lane*16
__device__ __forceinline__ void gload16(const u16* g, u16* l) {
  __builtin_amdgcn_global_load_lds(
      (const __attribute__((address_space(1))) void*)g,
      (__attribute__((address_space(3))) void*)l, 16, 0, 0);
}

// ==================== unified MFMA GEMM, 192x64 tile, two-panel BK=64 ====================
// Tile: 192 rows x 64 cols; 4 waves, wave w owns rows [w*48, w*48+48) x all 64 cols.
// Grid: (M/192, N/64) -> exact multiple of 256 blocks for our shapes.
// MODE 0: Cf = v              MODE 1: Cb = bf16(gelu(v))
// MODE 2: Cf += v             MODE 3: decoder scatter out = v + bias
// MODE 4: Cf += v + bf2f(Db)  MODE 5: Cf += v; Cb = bf16(Cf)
// MODE 6: Cb = bf16(v)
template <int TN, int MODE>
__global__ __launch_bounds__(256) void gemm_kernel(
    const u16* __restrict__ A, const u16* __restrict__ Bt, int K, int ldc,
    float* __restrict__ Cf, u16* __restrict__ Cb,
    const float* __restrict__ bias, const u16* __restrict__ Db) {
  static_assert(TN == 64, "192x64 tile only");
  __shared__ u16 As[2][192 * 32];
  __shared__ u16 Bs[2][64 * 32];
  const int m0 = blockIdx.x * 192, n0 = blockIdx.y * 64;
  const int tid = threadIdx.x;
  const int lane = tid & 63, w = tid >> 6;
  const int lane15 = lane & 15, quad = lane >> 4;
  const int r0 = lane >> 2, e0 = (lane & 3) * 8;

  const u16* ag0 = A + (size_t)(m0 + w * 48 + r0) * K + e0;
  const u16* ag1 = ag0 + (size_t)16 * K;
  const u16* ag2 = ag0 + (size_t)32 * K;
  const u16* bg0 = Bt + (size_t)(n0 + w * 16 + r0) * K + e0;

  f32x4 acc[3][4] = {};
  const int abase = (w * 48 + lane15) * 32 + quad * 8;
  const int bbase = lane15 * 32 + quad * 8;

  for (int k0 = 0; k0 < K; k0 += 64) {
#pragma unroll
    for (int p = 0; p < 2; ++p) {
      const int kk = k0 + 32 * p;
      gload16(ag0 + kk, &As[p][(w * 48) * 32]);
      gload16(ag1 + kk, &As[p][(w * 48 + 16) * 32]);
      gload16(ag2 + kk, &As[p][(w * 48 + 32) * 32]);
      gload16(bg0 + kk, &Bs[p][(w * 16) * 32]);
    }
    __syncthreads();
#pragma unroll
    for (int p = 0; p < 2; ++p) {
      bf16x8 af[3], bf[4];
#pragma unroll
      for (int i = 0; i < 3; ++i) af[i] = *(const bf16x8*)&As[p][abase + i * 16 * 32];
#pragma unroll
      for (int j = 0; j < 4; ++j) bf[j] = *(const bf16x8*)&Bs[p][bbase + j * 16 * 32];
#pragma unroll
      for (int i = 0; i < 3; ++i)
#pragma unroll
        for (int j = 0; j < 4; ++j)
          acc[i][j] = __builtin_amdgcn_mfma_f32_16x16x32_bf16(af[i], bf[j], acc[i][j], 0, 0, 0);
    }
    __syncthreads();
  }

  const int mw = m0 + w * 48;
#pragma unroll
  for (int i = 0; i < 3; ++i) {
#pragma unroll
    for (int j = 0; j < 4; ++j) {
      const int col = n0 + j * 16 + lane15;
#pragma unroll
      for (int r = 0; r < 4; ++r) {
        const int row = mw + i * 16 + quad * 4 + r;
        const float v = acc[i][j][r];
        const size_t idx = (size_t)row * ldc + col;
        if (MODE == 0) {
          Cf[idx] = v;
        } else if (MODE == 1) {
          Cb[idx] = f2bf(gelu_tanh(v));
        } else if (MODE == 2) {
          Cf[idx] += v;
        } else if (MODE == 3) {
          const int frame = row >> 8, pix = row & 255;
          const int hp = pix >> 4, wp = pix & 15;
          const int co = col >> 8, p1 = (col >> 4) & 15, p2 = col & 15;
          Cf[(((size_t)frame * 4 + co) * 256 + hp * 16 + p1) * 256 + wp * 16 + p2] = v + bias[col];
        } else if (MODE == 4) {
          Cf[idx] += v + bf2f(Db[idx]);
        } else if (MODE == 5) {
          const float nz = Cf[idx] + v;
          Cf[idx] = nz;
          Cb[idx] = f2bf(nz);
        } else if (MODE == 6) {
          Cb[idx] = f2bf(v);
        }
      }
    }
  }
}

// ==================== conv3x3 implicit-GEMM, 192x64 tile ====================
// dx-tap fusion: stage an 18-col halo strip per 16-row segment (each segment is
// exactly one pixel-row); the 3 dx-taps read LDS at compile-time row shifts.
// Outer loop dy(3) x kc(12) -> 36 barrier-pairs/block (was 108), 72 MFMA/wave/pair.
// LDS 52,224 B -> exactly 3 blocks/CU resident (grid 768 = 3/CU).
__global__ __launch_bounds__(256) void conv_mfma_kernel(
    const u16* __restrict__ xnp, const u16* __restrict__ Btc,
    const float* __restrict__ cbias,
    float* __restrict__ z, u16* __restrict__ zb) {
  __shared__ u16 As[2][4 * 3 * 18 * 32];  // [panel][wave][seg][halo-col 0..17][32K]
  __shared__ u16 Bs[2][3 * 64 * 32];      // [panel][dx][row 0..63][32K]
  const int m0 = blockIdx.x * 192, n0 = blockIdx.y * 64;
  const int tid = threadIdx.x;
  const int lane = tid & 63, w = tid >> 6;
  const int lane15 = lane & 15, quad = lane >> 4;
  const int r0 = lane >> 2, e0 = (lane & 3) * 8;

  // per-segment halo base: f*324 + hp*18 (dy*18 added in loop); seg = one pixel-row
  int fhp[3];
#pragma unroll
  for (int s = 0; s < 3; ++s) {
    const int rA = m0 + w * 48 + s * 16;
    fhp[s] = (rA >> 8) * 324 + ((rA & 255) >> 4) * 18;
  }
  const u16* bgt = Btc + (size_t)(n0 + w * 16 + r0) * 6912 + e0;

  f32x4 acc[3][4] = {};
  const int aseg = w * 3 * 18 * 32;  // wave's A base within a panel

  for (int dy = 0; dy < 3; ++dy) {
    const u16* asrc[3];
#pragma unroll
    for (int s = 0; s < 3; ++s)
      asrc[s] = xnp + ((size_t)(fhp[s] + dy * 18 + r0)) * 768 + e0;
    const u16* bsrc = bgt + dy * 3 * 768;

    for (int kc = 0; kc < 768; kc += 64) {
#pragma unroll
      for (int p = 0; p < 2; ++p) {
        const int kk = kc + 32 * p;
#pragma unroll
        for (int s = 0; s < 3; ++s) {
          // halo cols 0..15, then 2..17 (rows 2..15 rewritten with identical bytes)
          gload16(asrc[s] + kk, &As[p][aseg + s * 18 * 32]);
          gload16(asrc[s] + kk + 2 * 768, &As[p][aseg + s * 18 * 32 + 2 * 32]);
        }
#pragma unroll
        for (int dx = 0; dx < 3; ++dx)
          gload16(bsrc + dx * 768 + kk, &Bs[p][(dx * 64 + w * 16) * 32]);
      }
      __syncthreads();
#pragma unroll
      for (int p = 0; p < 2; ++p) {
#pragma unroll
        for (int dx = 0; dx < 3; ++dx) {
          bf16x8 af[3], bf[4];
#pragma unroll
          for (int i = 0; i < 3; ++i)
            af[i] = *(const bf16x8*)&As[p][aseg + (i * 18 + lane15 + dx) * 32 + quad * 8];
#pragma unroll
          for (int j = 0; j < 4; ++j)
            bf[j] = *(const bf16x8*)&Bs[p][(dx * 64 + j * 16 + lane15) * 32 + quad * 8];
#pragma unroll
          for (int i = 0; i < 3; ++i)
#pragma unroll
            for (int j = 0; j < 4; ++j)
              acc[i][j] = __builtin_amdgcn_mfma_f32_16x16x32_bf16(af[i], bf[j], acc[i][j], 0, 0, 0);
        }
      }
      __syncthreads();
    }
  }

  const int mw = m0 + w * 48;
#pragma unroll
  for (int i = 0; i < 3; ++i) {
#pragma unroll
    for (int j = 0; j < 4; ++j) {
      const int col = n0 + j * 16 + lane15;
      const float bv = cbias[col];
#pragma unroll
      for (int r = 0; r < 4; ++r) {
        const int row = mw + i * 16 + quad * 4 + r;
        const size_t idx = (size_t)row * 768 + col;
        const float nz = z[idx] + acc[i][j][r] + bv;
        z[idx] = nz;
        zb[idx] = f2bf(nz);
      }
    }
  }
}

// ==================== encoder: patch-embed MFMA (fp32->bf16 staging, runs once) ====================
__global__ __launch_bounds__(256) void encoder_mfma_kernel(
    const float* __restrict__ x, const float* __restrict__ ew,
    const float* __restrict__ eb, float* __restrict__ z) {
  __shared__ u16 As[128 * 32];
  __shared__ u16 Bs[128 * 32];
  const int m0 = blockIdx.x * 128, n0 = blockIdx.y * 128;
  const int tid = threadIdx.x;
  const int lane = tid & 63, w = tid >> 6;
  const int lane15 = lane & 15, quad = lane >> 4;
  const int srow = tid >> 1, half = tid & 1;
  const int arow = m0 + srow;
  const int frame = arow >> 8, pix = arow & 255, hh = pix >> 4, ww = pix & 15;

  f32x4 acc[4][4] = {};
  const int wy = w >> 1, wx = w & 1;
  const int ar_base = (wy * 64 + lane15) * 32 + quad * 8;
  const int br_base = (wx * 64 + lane15) * 32 + quad * 8;

  for (int k0 = 0; k0 < 1024; k0 += 32) {
    const int gk = k0 + half * 16;
    const int c = gk >> 8, ph = (gk >> 4) & 15;
    const float* ax = x + (((size_t)(frame * 4 + c) * 256 + hh * 16 + ph) * 256 + ww * 16);
    const float* bx = ew + (size_t)(n0 + srow) * 1024 + gk;
    u16 ta[16], tb[16];
#pragma unroll
    for (int j = 0; j < 4; ++j) {
      const float4 va = *(const float4*)(ax + j * 4);
      const float4 vb = *(const float4*)(bx + j * 4);
      ta[j * 4 + 0] = f2bf(va.x); ta[j * 4 + 1] = f2bf(va.y);
      ta[j * 4 + 2] = f2bf(va.z); ta[j * 4 + 3] = f2bf(va.w);
      tb[j * 4 + 0] = f2bf(vb.x); tb[j * 4 + 1] = f2bf(vb.y);
      tb[j * 4 + 2] = f2bf(vb.z); tb[j * 4 + 3] = f2bf(vb.w);
    }
    __syncthreads();
    *(uint4*)&As[srow * 32 + half * 16] = *(uint4*)ta;
    *(uint4*)&As[srow * 32 + half * 16 + 8] = *(uint4*)(ta + 8);
    *(uint4*)&Bs[srow * 32 + half * 16] = *(uint4*)tb;
    *(uint4*)&Bs[srow * 32 + half * 16 + 8] = *(uint4*)(tb + 8);
    __syncthreads();
    bf16x8 af[4], bfv[4];
#pragma unroll
    for (int i = 0; i < 4; ++i) af[i] = *(const bf16x8*)&As[ar_base + i * 16 * 32];
#pragma unroll
    for (int j = 0; j < 4; ++j) bfv[j] = *(const bf16x8*)&Bs[br_base + j * 16 * 32];
#pragma unroll
    for (int i = 0; i < 4; ++i)
#pragma unroll
      for (int j = 0; j < 4; ++j)
        acc[i][j] = __builtin_amdgcn_mfma_f32_16x16x32_bf16(af[i], bfv[j], acc[i][j], 0, 0, 0);
  }

  const int mw = m0 + wy * 64, nw = n0 + wx * 64;
#pragma unroll
  for (int i = 0; i < 4; ++i)
#pragma unroll
    for (int j = 0; j < 4; ++j) {
      const int col = nw + j * 16 + lane15;
      const float bv = eb[col];
#pragma unroll
      for (int r = 0; r < 4; ++r) {
        const int row = mw + i * 16 + quad * 4 + r;
        z[(size_t)row * 768 + col] = acc[i][j][r] + bv;
      }
    }
}

// ==================== weight prep ====================
__global__ __launch_bounds__(256) void expand_kernel(
    const float* __restrict__ Wre, const float* __restrict__ Wim,
    int ldw, int Kc, int Nc, u16* __restrict__ Wt) {
  __shared__ float tile[32][33];
  const int k0 = blockIdx.x * 32, n0 = blockIdx.y * 32;
  const bool khi = k0 >= Kc, nhi = n0 >= Nc;
  const float* src = (khi != nhi) ? Wim : Wre;
  const float sgn = (!nhi && khi) ? -1.0f : 1.0f;
  const int sk = k0 - (khi ? Kc : 0), sn = n0 - (nhi ? Nc : 0);
  const int c = threadIdx.x & 31, r8 = threadIdx.x >> 5;
  for (int r = r8; r < 32; r += 8)
    tile[r][c] = src[(size_t)(sk + r) * ldw + sn + c];
  __syncthreads();
  const int twoK = 2 * Kc;
  for (int r = r8; r < 32; r += 8)
    Wt[(size_t)(n0 + r) * twoK + k0 + c] = f2bf(sgn * tile[c][r]);
}

__global__ __launch_bounds__(256) void reorder_cw_kernel(
    const float* __restrict__ cwl, u16* __restrict__ Btc) {
  __shared__ float buf[6912];
  const int o = blockIdx.x;
  const float* src = cwl + (size_t)o * 6912;
  for (int i = threadIdx.x; i < 6912; i += 256) buf[i] = src[i];
  __syncthreads();
  u16* dst = Btc + (size_t)o * 6912;
  for (int i = threadIdx.x; i < 6912; i += 256) {
    const int tap = i / 768, cc = i - tap * 768;
    dst[i] = f2bf(buf[cc * 9 + tap]);
  }
}

__global__ __launch_bounds__(256) void cast_bf16_kernel(
    const float* __restrict__ in, u16* __restrict__ out, int n) {
  const int g = blockIdx.x * 256 + threadIdx.x;
  if (g < n) out[g] = f2bf(in[g]);
}

// ==================== LayerNorm fp32-in (halo writer) ====================
__global__ __launch_bounds__(192) void ln_kernel(
    const float* __restrict__ in, const float* __restrict__ g,
    const float* __restrict__ b, u16* __restrict__ out) {
  const int row = blockIdx.x, tid = threadIdx.x;
  const float4 v = *(const float4*)(in + (size_t)row * 768 + tid * 4);
  float s = v.x + v.y + v.z + v.w;
  float q = v.x * v.x + v.y * v.y + v.z * v.z + v.w * v.w;
#pragma unroll
  for (int off = 32; off > 0; off >>= 1) {
    s += __shfl_down(s, off);
    q += __shfl_down(q, off);
  }
  __shared__ float rs[3], rq[3];
  if ((tid & 63) == 0) { rs[tid >> 6] = s; rq[tid >> 6] = q; }
  __syncthreads();
  const float S = rs[0] + rs[1] + rs[2], Q = rq[0] + rq[1] + rq[2];
  const float mean = S * (1.0f / 768.0f);
  const float inv = rsqrtf(Q * (1.0f / 768.0f) - mean * mean + 1e-5f);
  const float4 gv = *(const float4*)(g + tid * 4);
  const float4 bv = *(const float4*)(b + tid * 4);
  u16 p[4];
  p[0] = f2bf((v.x - mean) * inv * gv.x + bv.x);
  p[1] = f2bf((v.y - mean) * inv * gv.y + bv.y);
  p[2] = f2bf((v.z - mean) * inv * gv.z + bv.z);
  p[3] = f2bf((v.w - mean) * inv * gv.w + bv.w);
  const int f = row >> 8, pp = row & 255, h = pp >> 4, ww = pp & 15;
  const size_t base = ((size_t)f * 324 + (h + 1) * 18 + ww + 1) * 768;
  *(uint2*)(out + base + tid * 4) = *(uint2*)p;
}

// ==================== LayerNorm bf16-in (flat writer) ====================
__global__ __launch_bounds__(192) void ln_bf_kernel(
    const u16* __restrict__ in, const float* __restrict__ g,
    const float* __restrict__ b, u16* __restrict__ out) {
  const int row = blockIdx.x, tid = threadIdx.x;
  const uint2 raw = *(const uint2*)(in + (size_t)row * 768 + tid * 4);
  const u16* rp = (const u16*)&raw;
  const float v0 = bf2f(rp[0]), v1 = bf2f(rp[1]), v2 = bf2f(rp[2]), v3 = bf2f(rp[3]);
  float s = v0 + v1 + v2 + v3;
  float q = v0 * v0 + v1 * v1 + v2 * v2 + v3 * v3;
#pragma unroll
  for (int off = 32; off > 0; off >>= 1) {
    s += __shfl_down(s, off);
    q += __shfl_down(q, off);
  }
  __shared__ float rs[3], rq[3];
  if ((tid & 63) == 0) { rs[tid >> 6] = s; rq[tid >> 6] = q; }
  __syncthreads();
  const float S = rs[0] + rs[1] + rs[2], Q = rq[0] + rq[1] + rq[2];
  const float mean = S * (1.0f / 768.0f);
  const float inv = rsqrtf(Q * (1.0f / 768.0f) - mean * mean + 1e-5f);
  const float4 gv = *(const float4*)(g + tid * 4);
  const float4 bv = *(const float4*)(b + tid * 4);
  u16 p[4];
  p[0] = f2bf((v0 - mean) * inv * gv.x + bv.x);
  p[1] = f2bf((v1 - mean) * inv * gv.y + bv.y);
  p[2] = f2bf((v2 - mean) * inv * gv.z + bv.z);
  p[3] = f2bf((v3 - mean) * inv * gv.w + bv.w);
  *(uint2*)(out + (size_t)row * 768 + tid * 4) = *(uint2*)p;
}

// ==================== mean over 256 pixels (bf16 in) ====================
__global__ __launch_bounds__(768) void mean_kernel(
    const u16* __restrict__ eig, float* __restrict__ mr, float* __restrict__ mi) {
  const int f = blockIdx.x, c = threadIdx.x;
  const u16* p = eig + (size_t)f * 256 * 768 + c;
  float s0 = 0.f, s1 = 0.f, s2 = 0.f, s3 = 0.f;
  for (int px = 0; px < 256; px += 4) {
    s0 += bf2f(p[(size_t)px * 768]);
    s1 += bf2f(p[(size_t)(px + 1) * 768]);
    s2 += bf2f(p[(size_t)(px + 2) * 768]);
    s3 += bf2f(p[(size_t)(px + 3) * 768]);
  }
  const float tot = (s0 + s1 + s2 + s3) * (1.0f / 256.0f);
  if (c < 384) mr[f * 384 + c] = tot;
  else         mi[f * 384 + c - 384] = tot;
}

// ==================== flux scan + operator precompute ====================
__global__ __launch_bounds__(384) void flux_kernel(
    const float* __restrict__ dt, const float* __restrict__ lamf,
    const float* __restrict__ nu, const float* __restrict__ omega,
    const float* __restrict__ mr, const float* __restrict__ mi,
    float* __restrict__ fluxr, float* __restrict__ fluxi,
    float* __restrict__ opdr, float* __restrict__ opdi,
    float* __restrict__ opfr, float* __restrict__ opfi) {
  const int b = blockIdx.x;
  const int d = threadIdx.x;
  const float sp = softplus_f(lamf[d]);
  float lre = -softplus_f(nu[d]);
  lre = fmaxf(lre, -5.0f);
  const float lim = omega[d];
  const float den = lre * lre + lim * lim;
  float fr = 0.f, fi = 0.f;
  for (int t = 0; t < 12; ++t) {
    const float dtv = dt[b * 12 + t];
    const int idx = (b * 12 + t) * 384 + d;
    const float A = expf(-sp * dtv);
    fr = A * fr + mr[idx] * dtv;
    fi = A * fi + mi[idx] * dtv;
    fluxr[idx] = fr; fluxi[idx] = fi;
    const float ed = expf(lre * dtv);
    const float odr = ed * cosf(lim * dtv);
    const float odi = ed * sinf(lim * dtv);
    opdr[idx] = odr; opdi[idx] = odi;
    const float nr_ = odr - 1.0f, ni_ = odi;
    opfr[idx] = (nr_ * lre + ni_ * lim) / den;
    opfi[idx] = (ni_ * lre - nr_ * lim) / den;
  }
}

// ==================== small fp32 complex GEMM + gate-product epilogue ====================
#define SBM 64
#define SBN 64
#define SBK 32
__global__ __launch_bounds__(256) void cgemm_src_kernel(
    const float* __restrict__ Ar, const float* __restrict__ Ai, int lda,
    const float* __restrict__ Wr, const float* __restrict__ Wi, int ldw,
    const float* __restrict__ Wg,
    float* __restrict__ G, float* __restrict__ SGr, float* __restrict__ SGi,
    int ldc, int M, int K) {
  __shared__ float Asr[SBK][SBM], Asi[SBK][SBM];
  __shared__ float Wsr[SBK][SBN], Wsi[SBK][SBN];
  const int m0 = blockIdx.x * SBM;
  const int n0 = blockIdx.y * SBN;
  const int tid = threadIdx.x;
  const int tn = tid & 15, tm = tid >> 4;
  float accr[4][4] = {}, acci[4][4] = {};
  for (int k0 = 0; k0 < K; k0 += SBK) {
    for (int s = tid; s < 512; s += 256) {
      {
        int r = s >> 3, kk = (s & 7) << 2;
        int row = m0 + r;
        float4 vr = {0.f, 0.f, 0.f, 0.f}, vi = {0.f, 0.f, 0.f, 0.f};
        if (row < M) {
          vr = *(const float4*)(Ar + (size_t)row * lda + k0 + kk);
          vi = *(const float4*)(Ai + (size_t)row * lda + k0 + kk);
        }
        Asr[kk + 0][r] = vr.x; Asr[kk + 1][r] = vr.y; Asr[kk + 2][r] = vr.z; Asr[kk + 3][r] = vr.w;
        Asi[kk + 0][r] = vi.x; Asi[kk + 1][r] = vi.y; Asi[kk + 2][r] = vi.z; Asi[kk + 3][r] = vi.w;
      }
      {
        int wr_ = s >> 4, wc = (s & 15) << 2;
        *(float4*)&Wsr[wr_][wc] = *(const float4*)(Wr + (size_t)(k0 + wr_) * ldw + n0 + wc);
        *(float4*)&Wsi[wr_][wc] = *(const float4*)(Wi + (size_t)(k0 + wr_) * ldw + n0 + wc);
      }
    }
    __syncthreads();
#pragma unroll
    for (int kk = 0; kk < SBK; ++kk) {
      float4 ar4 = *(const float4*)&Asr[kk][tm << 2];
      float4 ai4 = *(const float4*)&Asi[kk][tm << 2];
      float4 wr4 = *(const float4*)&Wsr[kk][tn << 2];
      float4 wi4 = *(const float4*)&Wsi[kk][tn << 2];
      float ar[4] = {ar4.x, ar4.y, ar4.z, ar4.w};
      float ai[4] = {ai4.x, ai4.y, ai4.z, ai4.w};
      float wr[4] = {wr4.x, wr4.y, wr4.z, wr4.w};
      float wi[4] = {wi4.x, wi4.y, wi4.z, wi4.w};
#pragma unroll
      for (int i = 0; i < 4; ++i)
#pragma unroll
        for (int j = 0; j < 4; ++j) {
          accr[i][j] = fmaf(ar[i], wr[j], accr[i][j]);
          accr[i][j] = fmaf(-ai[i], wi[j], accr[i][j]);
          acci[i][j] = fmaf(ar[i], wi[j], acci[i][j]);
          acci[i][j] = fmaf(ai[i], wr[j], acci[i][j]);
        }
    }
    __syncthreads();
  }
#pragma unroll
  for (int i = 0; i < 4; ++i) {
    int row = m0 + (tm << 2) + i;
    if (row >= M) continue;
#pragma unroll
    for (int j = 0; j < 4; ++j) {
      int col = n0 + (tn << 2) + j;
      size_t idx = (size_t)row * ldc + col;
      const float gate = 1.0f / (1.0f + expf(-Ar[idx] * Wg[col]));
      G[idx] = gate;
      SGr[idx] = accr[i][j] * (1.0f - gate);
      SGi[idx] = acci[i][j] * (1.0f - gate);
    }
  }
}

// ==================== fused forcing + u_out pscan (bf16 in) -> bf16 ub ====================
__global__ __launch_bounds__(256) void pscan_fused_kernel(
    const u16* __restrict__ eig,
    const float* __restrict__ Gv,
    const float* __restrict__ SGr, const float* __restrict__ SGi,
    const float* __restrict__ opfr, const float* __restrict__ opfi,
    const float* __restrict__ opdr, const float* __restrict__ opdi,
    u16* __restrict__ ub) {
  const int g = blockIdx.x * 256 + threadIdx.x;
  if (g >= 4 * 256 * 384) return;
  const int d = g % 384;
  const int pix = (g / 384) & 255;
  const int b = g / (384 * 256);
  float ur = 0.f, ui = 0.f;
  for (int t = 0; t < 12; ++t) {
    const int frame = b * 12 + t;
    const size_t idx = ((size_t)frame * 256 + pix) * 768 + d;
    const int fidx = frame * 384 + d;
    const float G = Gv[fidx];
    const float fr = bf2f(eig[idx]) * G + SGr[fidx];
    const float fi = bf2f(eig[idx + 384]) * G + SGi[fidx];
    const float pr = opfr[fidx], pi = opfi[fidx];
    const float utr = fr * pr - fi * pi;
    const float uti = fr * pi + fi * pr;
    const float ar = opdr[fidx], ai = opdi[fidx];
    const float nr = ar * ur - ai * ui + utr;
    const float ni = ar * ui + ai * ur + uti;
    ub[idx] = f2bf(nr); ub[idx + 384] = f2bf(ni);
    ur = nr; ui = ni;
  }
}

extern "C" void kernel_launch(void* const* d_in, const int* in_sizes, int n_in,
                              void* d_out, int out_size, void* d_ws, size_t ws_size,
                              hipStream_t stream) {
  const float* x        = (const float*)d_in[0];
  const float* dt       = (const float*)d_in[1];
  const float* enc_w    = (const float*)d_in[2];
  const float* enc_b    = (const float*)d_in[3];
  const float* ns_g     = (const float*)d_in[4];
  const float* ns_b     = (const float*)d_in[5];
  const float* cw       = (const float*)d_in[6];
  const float* cb       = (const float*)d_in[7];
  const float* nt_g     = (const float*)d_in[8];
  const float* nt_b     = (const float*)d_in[9];
  const float* E_re     = (const float*)d_in[10];
  const float* E_im     = (const float*)d_in[11];
  const float* Ei_re    = (const float*)d_in[12];
  const float* Ei_im    = (const float*)d_in[13];
  const float* lam_flux = (const float*)d_in[14];
  const float* Ws_re    = (const float*)d_in[15];
  const float* Ws_im    = (const float*)d_in[16];
  const float* Wg       = (const float*)d_in[17];
  const float* nu       = (const float*)d_in[18];
  const float* omega    = (const float*)d_in[19];
  const float* w1_re    = (const float*)d_in[20];
  const float* w1_im    = (const float*)d_in[21];
  const float* w2_re    = (const float*)d_in[22];
  const float* w2_im    = (const float*)d_in[23];
  const float* dec_w    = (const float*)d_in[24];
  const float* dec_b    = (const float*)d_in[25];
  float* out = (float*)d_out;

  const size_t NPF = 12288ull * 768;        // 9,437,184
  const size_t XNP = 48ull * 324 * 768;     // halo-padded plane
  const size_t SM = 48ull * 384;

  float* z    = (float*)d_ws;                // [12288][768] fp32 residual master
  float* eigf = z + NPF;                     // region A (NPF floats)
  float* dff  = eigf + NPF;                  // region B (NPF floats)
  u16* xnp    = (u16*)(dff + NPF);           // halo xnbp / flat xnb / ub
  u16* Btc    = xnp + XNP;                   // [768][6912]
  u16* Et     = Btc + 5308416;               // [768][768]
  u16* Eit    = Et + 589824;
  u16* W1t    = Eit + 589824;                // 2 chunks x [1536][768]
  u16* W2t    = W1t + 2359296;               // 2 chunks x [768][1536]
  u16* dwt    = W2t + 2359296;               // [1024][768]
  float* sm   = (float*)(dwt + 786432);
  float* mr    = sm;            float* mi    = mr + SM;
  float* fluxr = mi + SM;       float* fluxi = fluxr + SM;
  float* opdr  = fluxi + SM;    float* opdi  = opdr + SM;
  float* opfr  = opdi + SM;     float* opfi  = opfr + SM;
  float* Gv    = opfi + SM;     float* SGr   = Gv + SM;
  float* SGi   = SGr + SM;

  const size_t need = ((char*)(SGi + SM)) - ((char*)d_ws);
  if (ws_size < need) return;

  // region A: eig_b (bf16, first half) / h1b (bf16 FFN chunk, full region; disjoint lifetime)
  u16* eig_b = (u16*)eigf;
  u16* h1b   = (u16*)eigf;
  // region B: df_b (bf16, first half) + zbuf (bf16, second half)
  u16* df_b  = (u16*)dff;
  u16* zbuf  = (u16*)dff + NPF;

  cast_bf16_kernel<<<(786432 + 255) / 256, 256, 0, stream>>>(dec_w, dwt, 786432);
  encoder_mfma_kernel<<<dim3(96, 6), 256, 0, stream>>>(x, enc_w, enc_b, z);

  for (int l = 0; l < 4; ++l) {
    const size_t DD = 384ull * 384, DF = 384ull * 1536;
    hipMemsetAsync(xnp, 0, XNP * sizeof(u16), stream);  // zero halo borders
    reorder_cw_kernel<<<768, 256, 0, stream>>>(cw + (size_t)l * 768 * 768 * 9, Btc);
    expand_kernel<<<dim3(24, 24), 256, 0, stream>>>(E_re + l * DD, E_im + l * DD, 384, 384, 384, Et);
    expand_kernel<<<dim3(24, 24), 256, 0, stream>>>(Ei_re + l * DD, Ei_im + l * DD, 384, 384, 384, Eit);
    for (int ch = 0; ch < 2; ++ch) {
      expand_kernel<<<dim3(24, 48), 256, 0, stream>>>(
          w1_re + l * DF + ch * 768, w1_im + l * DF + ch * 768, 1536, 384, 768, W1t + (size_t)ch * 1179648);
      expand_kernel<<<dim3(48, 24), 256, 0, stream>>>(
          w2_re + l * DF + (size_t)ch * 768 * 384, w2_im + l * DF + (size_t)ch * 768 * 384, 384, 768, 384,
          W2t + (size_t)ch * 1179648);
    }

    ln_kernel<<<12288, 192, 0, stream>>>(z, ns_g + l * 768, ns_b + l * 768, xnp);
    conv_mfma_kernel<<<dim3(64, 12), 256, 0, stream>>>(xnp, Btc, cb + l * 768, z, zbuf);
    gemm_kernel<64, 6><<<dim3(64, 12), 256, 0, stream>>>(zbuf, Et, 768, 768, nullptr, eig_b, nullptr, nullptr);
    mean_kernel<<<48, 768, 0, stream>>>(eig_b, mr, mi);
    flux_kernel<<<4, 384, 0, stream>>>(dt, lam_flux + l * 384, nu + l * 384, omega + l * 384,
                                       mr, mi, fluxr, fluxi, opdr, opdi, opfr, opfi);
    cgemm_src_kernel<<<dim3(1, 6), 256, 0, stream>>>(
        fluxr, fluxi, 384, Ws_re + l * DD, Ws_im + l * DD, 384,
        Wg + l * 384, Gv, SGr, SGi, 384, 48, 384);
    pscan_fused_kernel<<<1536, 256, 0, stream>>>(eig_b, Gv, SGr, SGi, opfr, opfi, opdr, opdi, xnp);
    gemm_kernel<64, 6><<<dim3(64, 12), 256, 0, stream>>>(xnp, Eit, 768, 768, nullptr, df_b, nullptr, nullptr);
    ln_bf_kernel<<<12288, 192, 0, stream>>>(df_b, nt_g + l * 768, nt_b + l * 768, xnp);
    for (int ch = 0; ch < 2; ++ch) {
      gemm_kernel<64, 1><<<dim3(64, 24), 256, 0, stream>>>(
          xnp, W1t + (size_t)ch * 1179648, 768, 1536, nullptr, h1b, nullptr, nullptr);
      if (ch == 0) {
        // z += W2 + df (df-residual fused, bf16 df read)
        gemm_kernel<64, 4><<<dim3(64, 12), 256, 0, stream>>>(
            h1b, W2t, 1536, 768, z, nullptr, nullptr, df_b);
      } else if (l < 3) {
        gemm_kernel<64, 2><<<dim3(64, 12), 256, 0, stream>>>(
            h1b, W2t + 1179648, 1536, 768, z, nullptr, nullptr, nullptr);
      } else {
        // final layer: also emit zbuf for the decoder
        gemm_kernel<64, 5><<<dim3(64, 12), 256, 0, stream>>>(
            h1b, W2t + 1179648, 1536, 768, z, zbuf, nullptr, nullptr);
      }
    }
  }

  gemm_kernel<64, 3><<<dim3(64, 16), 256, 0, stream>>>(zbuf, dwt, 768, 0, out, nullptr, dec_b, nullptr);
}

// Round 3
// 2471.813 us; speedup vs baseline: 1.1356x; 1.0162x over previous
//
#include <hip/hip_runtime.h>
#include <cstddef>
#include <cstdint>

typedef unsigned short u16;
typedef short bf16x8 __attribute__((ext_vector_type(8)));
typedef float f32x4 __attribute__((ext_vector_type(4)));

__device__ __forceinline__ float gelu_tanh(float x) {
  float x3 = x * x * x;
  float t = tanhf(0.7978845608028654f * (x + 0.044715f * x3));
  return 0.5f * x * (1.0f + t);
}
__device__ __forceinline__ float softplus_f(float x) {
  return (x > 20.0f) ? x : log1pf(expf(x));
}
__device__ __forceinline__ u16 f2bf(float f) {
  uint32_t u = __float_as_uint(f);
  uint32_t r = (u + 0x7fffu + ((u >> 16) & 1u)) >> 16;
  return (u16)r;
}
__device__ __forceinline__ float bf2f(u16 v) {
  return __uint_as_float(((uint32_t)v) << 16);
}

// async global->LDS, 16B/lane; LDS dest = wave-uniform base + lane*16, global src per-lane
__device__ __forceinline__ void gload16(const u16* g, u16* l) {
  __builtin_amdgcn_global_load_lds(
      (const __attribute__((address_space(1))) void*)g,
      (__attribute__((address_space(3))) void*)l, 16, 0, 0);
}

// ==================== unified MFMA GEMM, 192x64 tile, two-panel BK=64 ====================
// MODE 0: Cf = v              MODE 1: Cb = bf16(gelu(v))
// MODE 2: Cf += v             MODE 3: decoder scatter out = v + bias
// MODE 4: Cf += v + bf2f(Db)  MODE 5: Cf += v; Cb = bf16(Cf)
// MODE 6: Cb = bf16(v)
template <int TN, int MODE>
__global__ __launch_bounds__(256) void gemm_kernel(
    const u16* __restrict__ A, const u16* __restrict__ Bt, int K, int ldc,
    float* __restrict__ Cf, u16* __restrict__ Cb,
    const float* __restrict__ bias, const u16* __restrict__ Db) {
  static_assert(TN == 64, "192x64 tile only");
  __shared__ u16 As[2][192 * 32];
  __shared__ u16 Bs[2][64 * 32];
  const int m0 = blockIdx.x * 192, n0 = blockIdx.y * 64;
  const int tid = threadIdx.x;
  const int lane = tid & 63, w = tid >> 6;
  const int lane15 = lane & 15, quad = lane >> 4;
  const int r0 = lane >> 2, e0 = (lane & 3) * 8;

  const u16* ag0 = A + (size_t)(m0 + w * 48 + r0) * K + e0;
  const u16* ag1 = ag0 + (size_t)16 * K;
  const u16* ag2 = ag0 + (size_t)32 * K;
  const u16* bg0 = Bt + (size_t)(n0 + w * 16 + r0) * K + e0;

  f32x4 acc[3][4] = {};
  const int abase = (w * 48 + lane15) * 32 + quad * 8;
  const int bbase = lane15 * 32 + quad * 8;

  for (int k0 = 0; k0 < K; k0 += 64) {
#pragma unroll
    for (int p = 0; p < 2; ++p) {
      const int kk = k0 + 32 * p;
      gload16(ag0 + kk, &As[p][(w * 48) * 32]);
      gload16(ag1 + kk, &As[p][(w * 48 + 16) * 32]);
      gload16(ag2 + kk, &As[p][(w * 48 + 32) * 32]);
      gload16(bg0 + kk, &Bs[p][(w * 16) * 32]);
    }
    __syncthreads();
#pragma unroll
    for (int p = 0; p < 2; ++p) {
      bf16x8 af[3], bf[4];
#pragma unroll
      for (int i = 0; i < 3; ++i) af[i] = *(const bf16x8*)&As[p][abase + i * 16 * 32];
#pragma unroll
      for (int j = 0; j < 4; ++j) bf[j] = *(const bf16x8*)&Bs[p][bbase + j * 16 * 32];
#pragma unroll
      for (int i = 0; i < 3; ++i)
#pragma unroll
        for (int j = 0; j < 4; ++j)
          acc[i][j] = __builtin_amdgcn_mfma_f32_16x16x32_bf16(af[i], bf[j], acc[i][j], 0, 0, 0);
    }
    __syncthreads();
  }

  const int mw = m0 + w * 48;
#pragma unroll
  for (int i = 0; i < 3; ++i) {
#pragma unroll
    for (int j = 0; j < 4; ++j) {
      const int col = n0 + j * 16 + lane15;
#pragma unroll
      for (int r = 0; r < 4; ++r) {
        const int row = mw + i * 16 + quad * 4 + r;
        const float v = acc[i][j][r];
        const size_t idx = (size_t)row * ldc + col;
        if (MODE == 0) {
          Cf[idx] = v;
        } else if (MODE == 1) {
          Cb[idx] = f2bf(gelu_tanh(v));
        } else if (MODE == 2) {
          Cf[idx] += v;
        } else if (MODE == 3) {
          const int frame = row >> 8, pix = row & 255;
          const int hp = pix >> 4, wp = pix & 15;
          const int co = col >> 8, p1 = (col >> 4) & 15, p2 = col & 15;
          Cf[(((size_t)frame * 4 + co) * 256 + hp * 16 + p1) * 256 + wp * 16 + p2] = v + bias[col];
        } else if (MODE == 4) {
          Cf[idx] += v + bf2f(Db[idx]);
        } else if (MODE == 5) {
          const float nz = Cf[idx] + v;
          Cf[idx] = nz;
          Cb[idx] = f2bf(nz);
        } else if (MODE == 6) {
          Cb[idx] = f2bf(v);
        }
      }
    }
  }
}

// ==================== conv3x3 implicit-GEMM, 192x64 tile, dx-fused ====================
// A staging per dy: the wave's 3 segments need 3 CONSECUTIVE halo strips =
// 54 contiguous halo positions. Fast path (no frame straddle, q<=13): 4
// overlapping gload16 (64 row-loads) instead of 6 (96). LDS layout identical
// (3*18*32 == 54*32), MFMA reads unchanged. Straddle waves use per-seg path.
__global__ __launch_bounds__(256) void conv_mfma_kernel(
    const u16* __restrict__ xnp, const u16* __restrict__ Btc,
    const float* __restrict__ cbias,
    float* __restrict__ z, u16* __restrict__ zb) {
  __shared__ u16 As[2][4 * 54 * 32];      // [panel][wave][halo-pos 0..53][32K]
  __shared__ u16 Bs[2][3 * 64 * 32];      // [panel][dx][row 0..63][32K]
  const int m0 = blockIdx.x * 192, n0 = blockIdx.y * 64;
  const int tid = threadIdx.x;
  const int lane = tid & 63, w = tid >> 6;
  const int lane15 = lane & 15, quad = lane >> 4;
  const int r0 = lane >> 2, e0 = (lane & 3) * 8;

  const int rowA0 = m0 + w * 48;               // wave base row (multiple of 48)
  const int q = (rowA0 >> 4) & 15;             // starting pixel-row within frame
  const bool fast = (q <= 13);                 // all 3 pixel-rows in one frame
  const long long cbase = ((long long)(rowA0 >> 8) * 324 + q * 18) * 768;

  // per-segment halo base for the straddle path
  int fhp[3];
#pragma unroll
  for (int s = 0; s < 3; ++s) {
    const int rA = rowA0 + s * 16;
    fhp[s] = (rA >> 8) * 324 + ((rA & 255) >> 4) * 18;
  }
  const u16* bgt = Btc + (size_t)(n0 + w * 16 + r0) * 6912 + e0;

  f32x4 acc[3][4] = {};
  const int aseg = w * 54 * 32;  // wave's A base within a panel

  for (int dy = 0; dy < 3; ++dy) {
    // fast path: 54 contiguous halo positions starting at strip (q+dy)
    const u16* afast = xnp + cbase + (size_t)dy * (18 * 768) + (size_t)r0 * 768 + e0;
    const u16* asrc[3];
#pragma unroll
    for (int s = 0; s < 3; ++s)
      asrc[s] = xnp + ((size_t)(fhp[s] + dy * 18 + r0)) * 768 + e0;
    const u16* bsrc = bgt + dy * 3 * 768;

    for (int kc = 0; kc < 768; kc += 64) {
#pragma unroll
      for (int p = 0; p < 2; ++p) {
        const int kk = kc + 32 * p;
        if (fast) {
          // positions 0-15, 16-31, 32-47, 38-53 (38-47 rewritten identically)
          gload16(afast + kk, &As[p][aseg]);
          gload16(afast + kk + 16 * 768, &As[p][aseg + 16 * 32]);
          gload16(afast + kk + 32 * 768, &As[p][aseg + 32 * 32]);
          gload16(afast + kk + 38 * 768, &As[p][aseg + 38 * 32]);
        } else {
#pragma unroll
          for (int s = 0; s < 3; ++s) {
            gload16(asrc[s] + kk, &As[p][aseg + s * 18 * 32]);
            gload16(asrc[s] + kk + 2 * 768, &As[p][aseg + s * 18 * 32 + 2 * 32]);
          }
        }
#pragma unroll
        for (int dx = 0; dx < 3; ++dx)
          gload16(bsrc + dx * 768 + kk, &Bs[p][(dx * 64 + w * 16) * 32]);
      }
      __syncthreads();
#pragma unroll
      for (int p = 0; p < 2; ++p) {
#pragma unroll
        for (int dx = 0; dx < 3; ++dx) {
          bf16x8 af[3], bf[4];
#pragma unroll
          for (int i = 0; i < 3; ++i)
            af[i] = *(const bf16x8*)&As[p][aseg + (i * 18 + lane15 + dx) * 32 + quad * 8];
#pragma unroll
          for (int j = 0; j < 4; ++j)
            bf[j] = *(const bf16x8*)&Bs[p][(dx * 64 + j * 16 + lane15) * 32 + quad * 8];
#pragma unroll
          for (int i = 0; i < 3; ++i)
#pragma unroll
            for (int j = 0; j < 4; ++j)
              acc[i][j] = __builtin_amdgcn_mfma_f32_16x16x32_bf16(af[i], bf[j], acc[i][j], 0, 0, 0);
        }
      }
      __syncthreads();
    }
  }

  const int mw = m0 + w * 48;
#pragma unroll
  for (int i = 0; i < 3; ++i) {
#pragma unroll
    for (int j = 0; j < 4; ++j) {
      const int col = n0 + j * 16 + lane15;
      const float bv = cbias[col];
#pragma unroll
      for (int r = 0; r < 4; ++r) {
        const int row = mw + i * 16 + quad * 4 + r;
        const size_t idx = (size_t)row * 768 + col;
        const float nz = z[idx] + acc[i][j][r] + bv;
        z[idx] = nz;
        zb[idx] = f2bf(nz);
      }
    }
  }
}

// ==================== encoder: patch-embed MFMA, 192x64 tile (runs once) ====================
__global__ __launch_bounds__(256) void encoder_mfma_kernel(
    const float* __restrict__ x, const float* __restrict__ ew,
    const float* __restrict__ eb, float* __restrict__ z) {
  __shared__ u16 As[192 * 32];
  __shared__ u16 Bs[64 * 32];
  const int m0 = blockIdx.x * 192, n0 = blockIdx.y * 64;
  const int tid = threadIdx.x;
  const int lane = tid & 63, w = tid >> 6;
  const int lane15 = lane & 15, quad = lane >> 4;

  f32x4 acc[3][4] = {};
  const int abase = (w * 48 + lane15) * 32 + quad * 8;
  const int bbase = lane15 * 32 + quad * 8;

  for (int k0 = 0; k0 < 1024; k0 += 32) {
    __syncthreads();
    // stage A: 192 rows x 32 k-cols (fp32 gather -> bf16), 3 passes x 8 floats
#pragma unroll
    for (int pass = 0; pass < 3; ++pass) {
      const int id = tid + pass * 256;  // 0..767
      const int row = id >> 2, kc8 = (id & 3) * 8;
      const int arow = m0 + row;
      const int frame = arow >> 8, pix = arow & 255, hh = pix >> 4, ww = pix & 15;
      const int gk = k0 + kc8;
      const int c = gk >> 8, ph = (gk >> 4) & 15, pw = gk & 15;
      const float* ax = x + (((size_t)(frame * 4 + c) * 256 + hh * 16 + ph) * 256 + ww * 16 + pw);
      const float4 v0 = *(const float4*)ax;
      const float4 v1 = *(const float4*)(ax + 4);
      u16 t8[8];
      t8[0] = f2bf(v0.x); t8[1] = f2bf(v0.y); t8[2] = f2bf(v0.z); t8[3] = f2bf(v0.w);
      t8[4] = f2bf(v1.x); t8[5] = f2bf(v1.y); t8[6] = f2bf(v1.z); t8[7] = f2bf(v1.w);
      *(uint4*)&As[row * 32 + kc8] = *(uint4*)t8;
    }
    // stage B: 64 rows x 32 k-cols
    {
      const int row = tid >> 2, kc8 = (tid & 3) * 8;
      const float* bx = ew + (size_t)(n0 + row) * 1024 + k0 + kc8;
      const float4 v0 = *(const float4*)bx;
      const float4 v1 = *(const float4*)(bx + 4);
      u16 t8[8];
      t8[0] = f2bf(v0.x); t8[1] = f2bf(v0.y); t8[2] = f2bf(v0.z); t8[3] = f2bf(v0.w);
      t8[4] = f2bf(v1.x); t8[5] = f2bf(v1.y); t8[6] = f2bf(v1.z); t8[7] = f2bf(v1.w);
      *(uint4*)&Bs[row * 32 + kc8] = *(uint4*)t8;
    }
    __syncthreads();
    bf16x8 af[3], bfv[4];
#pragma unroll
    for (int i = 0; i < 3; ++i) af[i] = *(const bf16x8*)&As[abase + i * 16 * 32];
#pragma unroll
    for (int j = 0; j < 4; ++j) bfv[j] = *(const bf16x8*)&Bs[bbase + j * 16 * 32];
#pragma unroll
    for (int i = 0; i < 3; ++i)
#pragma unroll
      for (int j = 0; j < 4; ++j)
        acc[i][j] = __builtin_amdgcn_mfma_f32_16x16x32_bf16(af[i], bfv[j], acc[i][j], 0, 0, 0);
  }

  const int mw = m0 + w * 48;
#pragma unroll
  for (int i = 0; i < 3; ++i)
#pragma unroll
    for (int j = 0; j < 4; ++j) {
      const int col = n0 + j * 16 + lane15;
      const float bv = eb[col];
#pragma unroll
      for (int r = 0; r < 4; ++r) {
        const int row = mw + i * 16 + quad * 4 + r;
        z[(size_t)row * 768 + col] = acc[i][j][r] + bv;
      }
    }
}

// ==================== mega weight-prep: all 6 expands + cw reorder in ONE launch ====================
// z: 0=E 1=Ei 2=W1ch0 3=W1ch1 4=W2ch0 5=W2ch1 6=reorder_cw (768 sub-blocks)
__global__ __launch_bounds__(256) void mega_expand_kernel(
    const float* __restrict__ E_re, const float* __restrict__ E_im,
    const float* __restrict__ Ei_re, const float* __restrict__ Ei_im,
    const float* __restrict__ w1_re, const float* __restrict__ w1_im,
    const float* __restrict__ w2_re, const float* __restrict__ w2_im,
    const float* __restrict__ cwl,
    u16* __restrict__ Et, u16* __restrict__ Eit,
    u16* __restrict__ W1t, u16* __restrict__ W2t, u16* __restrict__ Btc) {
  __shared__ float shbuf[6912];
  const int zz = blockIdx.z;

  if (zz == 6) {
    const int o = blockIdx.y * 48 + blockIdx.x;
    if (o >= 768) return;
    const float* src = cwl + (size_t)o * 6912;
    for (int i = threadIdx.x; i < 6912; i += 256) shbuf[i] = src[i];
    __syncthreads();
    u16* dst = Btc + (size_t)o * 6912;
    for (int i = threadIdx.x; i < 6912; i += 256) {
      const int tap = i / 768, cc = i - tap * 768;
      dst[i] = f2bf(shbuf[cc * 9 + tap]);
    }
    return;
  }

  const float *Wre, *Wim;
  int ldw, Kc, Nc, gx, gy;
  u16* Wt;
  const size_t DF = 384ull * 1536;
  switch (zz) {
    case 0:  Wre = E_re;  Wim = E_im;  ldw = 384;  Kc = 384; Nc = 384; Wt = Et;  gx = 24; gy = 24; break;
    case 1:  Wre = Ei_re; Wim = Ei_im; ldw = 384;  Kc = 384; Nc = 384; Wt = Eit; gx = 24; gy = 24; break;
    case 2:  Wre = w1_re; Wim = w1_im; ldw = 1536; Kc = 384; Nc = 768; Wt = W1t; gx = 24; gy = 48; break;
    case 3:  Wre = w1_re + 768; Wim = w1_im + 768; ldw = 1536; Kc = 384; Nc = 768;
             Wt = W1t + 1179648; gx = 24; gy = 48; break;
    case 4:  Wre = w2_re; Wim = w2_im; ldw = 384;  Kc = 768; Nc = 384; Wt = W2t; gx = 48; gy = 24; break;
    default: Wre = w2_re + DF / 2; Wim = w2_im + DF / 2; ldw = 384; Kc = 768; Nc = 384;
             Wt = W2t + 1179648; gx = 48; gy = 24; break;
  }
  if ((int)blockIdx.x >= gx || (int)blockIdx.y >= gy) return;

  float (*tile)[33] = (float(*)[33])shbuf;
  const int k0 = blockIdx.x * 32, n0 = blockIdx.y * 32;
  const bool khi = k0 >= Kc, nhi = n0 >= Nc;
  const float* src = (khi != nhi) ? Wim : Wre;
  const float sgn = (!nhi && khi) ? -1.0f : 1.0f;
  const int sk = k0 - (khi ? Kc : 0), sn = n0 - (nhi ? Nc : 0);
  const int c = threadIdx.x & 31, r8 = threadIdx.x >> 5;
  for (int r = r8; r < 32; r += 8)
    tile[r][c] = src[(size_t)(sk + r) * ldw + sn + c];
  __syncthreads();
  const int twoK = 2 * Kc;
  for (int r = r8; r < 32; r += 8)
    Wt[(size_t)(n0 + r) * twoK + k0 + c] = f2bf(sgn * tile[c][r]);
}

__global__ __launch_bounds__(256) void cast_bf16_kernel(
    const float* __restrict__ in, u16* __restrict__ out, int n) {
  const int g = blockIdx.x * 256 + threadIdx.x;
  if (g < n) out[g] = f2bf(in[g]);
}

// ==================== LayerNorm fp32-in (halo writer) ====================
__global__ __launch_bounds__(192) void ln_kernel(
    const float* __restrict__ in, const float* __restrict__ g,
    const float* __restrict__ b, u16* __restrict__ out) {
  const int row = blockIdx.x, tid = threadIdx.x;
  const float4 v = *(const float4*)(in + (size_t)row * 768 + tid * 4);
  float s = v.x + v.y + v.z + v.w;
  float q = v.x * v.x + v.y * v.y + v.z * v.z + v.w * v.w;
#pragma unroll
  for (int off = 32; off > 0; off >>= 1) {
    s += __shfl_down(s, off);
    q += __shfl_down(q, off);
  }
  __shared__ float rs[3], rq[3];
  if ((tid & 63) == 0) { rs[tid >> 6] = s; rq[tid >> 6] = q; }
  __syncthreads();
  const float S = rs[0] + rs[1] + rs[2], Q = rq[0] + rq[1] + rq[2];
  const float mean = S * (1.0f / 768.0f);
  const float inv = rsqrtf(Q * (1.0f / 768.0f) - mean * mean + 1e-5f);
  const float4 gv = *(const float4*)(g + tid * 4);
  const float4 bv = *(const float4*)(b + tid * 4);
  u16 p[4];
  p[0] = f2bf((v.x - mean) * inv * gv.x + bv.x);
  p[1] = f2bf((v.y - mean) * inv * gv.y + bv.y);
  p[2] = f2bf((v.z - mean) * inv * gv.z + bv.z);
  p[3] = f2bf((v.w - mean) * inv * gv.w + bv.w);
  const int f = row >> 8, pp = row & 255, h = pp >> 4, ww = pp & 15;
  const size_t base = ((size_t)f * 324 + (h + 1) * 18 + ww + 1) * 768;
  *(uint2*)(out + base + tid * 4) = *(uint2*)p;
}

// ==================== LayerNorm bf16-in (flat writer) ====================
__global__ __launch_bounds__(192) void ln_bf_kernel(
    const u16* __restrict__ in, const float* __restrict__ g,
    const float* __restrict__ b, u16* __restrict__ out) {
  const int row = blockIdx.x, tid = threadIdx.x;
  const uint2 raw = *(const uint2*)(in + (size_t)row * 768 + tid * 4);
  const u16* rp = (const u16*)&raw;
  const float v0 = bf2f(rp[0]), v1 = bf2f(rp[1]), v2 = bf2f(rp[2]), v3 = bf2f(rp[3]);
  float s = v0 + v1 + v2 + v3;
  float q = v0 * v0 + v1 * v1 + v2 * v2 + v3 * v3;
#pragma unroll
  for (int off = 32; off > 0; off >>= 1) {
    s += __shfl_down(s, off);
    q += __shfl_down(q, off);
  }
  __shared__ float rs[3], rq[3];
  if ((tid & 63) == 0) { rs[tid >> 6] = s; rq[tid >> 6] = q; }
  __syncthreads();
  const float S = rs[0] + rs[1] + rs[2], Q = rq[0] + rq[1] + rq[2];
  const float mean = S * (1.0f / 768.0f);
  const float inv = rsqrtf(Q * (1.0f / 768.0f) - mean * mean + 1e-5f);
  const float4 gv = *(const float4*)(g + tid * 4);
  const float4 bv = *(const float4*)(b + tid * 4);
  u16 p[4];
  p[0] = f2bf((v0 - mean) * inv * gv.x + bv.x);
  p[1] = f2bf((v1 - mean) * inv * gv.y + bv.y);
  p[2] = f2bf((v2 - mean) * inv * gv.z + bv.z);
  p[3] = f2bf((v3 - mean) * inv * gv.w + bv.w);
  *(uint2*)(out + (size_t)row * 768 + tid * 4) = *(uint2*)p;
}

// ==================== mean over 256 pixels (bf16 in) ====================
__global__ __launch_bounds__(768) void mean_kernel(
    const u16* __restrict__ eig, float* __restrict__ mr, float* __restrict__ mi) {
  const int f = blockIdx.x, c = threadIdx.x;
  const u16* p = eig + (size_t)f * 256 * 768 + c;
  float s0 = 0.f, s1 = 0.f, s2 = 0.f, s3 = 0.f;
  for (int px = 0; px < 256; px += 4) {
    s0 += bf2f(p[(size_t)px * 768]);
    s1 += bf2f(p[(size_t)(px + 1) * 768]);
    s2 += bf2f(p[(size_t)(px + 2) * 768]);
    s3 += bf2f(p[(size_t)(px + 3) * 768]);
  }
  const float tot = (s0 + s1 + s2 + s3) * (1.0f / 256.0f);
  if (c < 384) mr[f * 384 + c] = tot;
  else         mi[f * 384 + c - 384] = tot;
}

// ==================== flux scan + operator precompute ====================
__global__ __launch_bounds__(384) void flux_kernel(
    const float* __restrict__ dt, const float* __restrict__ lamf,
    const float* __restrict__ nu, const float* __restrict__ omega,
    const float* __restrict__ mr, const float* __restrict__ mi,
    float* __restrict__ fluxr, float* __restrict__ fluxi,
    float* __restrict__ opdr, float* __restrict__ opdi,
    float* __restrict__ opfr, float* __restrict__ opfi) {
  const int b = blockIdx.x;
  const int d = threadIdx.x;
  const float sp = softplus_f(lamf[d]);
  float lre = -softplus_f(nu[d]);
  lre = fmaxf(lre, -5.0f);
  const float lim = omega[d];
  const float den = lre * lre + lim * lim;
  float fr = 0.f, fi = 0.f;
  for (int t = 0; t < 12; ++t) {
    const float dtv = dt[b * 12 + t];
    const int idx = (b * 12 + t) * 384 + d;
    const float A = expf(-sp * dtv);
    fr = A * fr + mr[idx] * dtv;
    fi = A * fi + mi[idx] * dtv;
    fluxr[idx] = fr; fluxi[idx] = fi;
    const float ed = expf(lre * dtv);
    const float odr = ed * cosf(lim * dtv);
    const float odi = ed * sinf(lim * dtv);
    opdr[idx] = odr; opdi[idx] = odi;
    const float nr_ = odr - 1.0f, ni_ = odi;
    opfr[idx] = (nr_ * lre + ni_ * lim) / den;
    opfi[idx] = (ni_ * lre - nr_ * lim) / den;
  }
}

// ==================== small fp32 complex GEMM + gate-product epilogue ====================
#define SBM 64
#define SBN 64
#define SBK 32
__global__ __launch_bounds__(256) void cgemm_src_kernel(
    const float* __restrict__ Ar, const float* __restrict__ Ai, int lda,
    const float* __restrict__ Wr, const float* __restrict__ Wi, int ldw,
    const float* __restrict__ Wg,
    float* __restrict__ G, float* __restrict__ SGr, float* __restrict__ SGi,
    int ldc, int M, int K) {
  __shared__ float Asr[SBK][SBM], Asi[SBK][SBM];
  __shared__ float Wsr[SBK][SBN], Wsi[SBK][SBN];
  const int m0 = blockIdx.x * SBM;
  const int n0 = blockIdx.y * SBN;
  const int tid = threadIdx.x;
  const int tn = tid & 15, tm = tid >> 4;
  float accr[4][4] = {}, acci[4][4] = {};
  for (int k0 = 0; k0 < K; k0 += SBK) {
    for (int s = tid; s < 512; s += 256) {
      {
        int r = s >> 3, kk = (s & 7) << 2;
        int row = m0 + r;
        float4 vr = {0.f, 0.f, 0.f, 0.f}, vi = {0.f, 0.f, 0.f, 0.f};
        if (row < M) {
          vr = *(const float4*)(Ar + (size_t)row * lda + k0 + kk);
          vi = *(const float4*)(Ai + (size_t)row * lda + k0 + kk);
        }
        Asr[kk + 0][r] = vr.x; Asr[kk + 1][r] = vr.y; Asr[kk + 2][r] = vr.z; Asr[kk + 3][r] = vr.w;
        Asi[kk + 0][r] = vi.x; Asi[kk + 1][r] = vi.y; Asi[kk + 2][r] = vi.z; Asi[kk + 3][r] = vi.w;
      }
      {
        int wr_ = s >> 4, wc = (s & 15) << 2;
        *(float4*)&Wsr[wr_][wc] = *(const float4*)(Wr + (size_t)(k0 + wr_) * ldw + n0 + wc);
        *(float4*)&Wsi[wr_][wc] = *(const float4*)(Wi + (size_t)(k0 + wr_) * ldw + n0 + wc);
      }
    }
    __syncthreads();
#pragma unroll
    for (int kk = 0; kk < SBK; ++kk) {
      float4 ar4 = *(const float4*)&Asr[kk][tm << 2];
      float4 ai4 = *(const float4*)&Asi[kk][tm << 2];
      float4 wr4 = *(const float4*)&Wsr[kk][tn << 2];
      float4 wi4 = *(const float4*)&Wsi[kk][tn << 2];
      float ar[4] = {ar4.x, ar4.y, ar4.z, ar4.w};
      float ai[4] = {ai4.x, ai4.y, ai4.z, ai4.w};
      float wr[4] = {wr4.x, wr4.y, wr4.z, wr4.w};
      float wi[4] = {wi4.x, wi4.y, wi4.z, wi4.w};
#pragma unroll
      for (int i = 0; i < 4; ++i)
#pragma unroll
        for (int j = 0; j < 4; ++j) {
          accr[i][j] = fmaf(ar[i], wr[j], accr[i][j]);
          accr[i][j] = fmaf(-ai[i], wi[j], accr[i][j]);
          acci[i][j] = fmaf(ar[i], wi[j], acci[i][j]);
          acci[i][j] = fmaf(ai[i], wr[j], acci[i][j]);
        }
    }
    __syncthreads();
  }
#pragma unroll
  for (int i = 0; i < 4; ++i) {
    int row = m0 + (tm << 2) + i;
    if (row >= M) continue;
#pragma unroll
    for (int j = 0; j < 4; ++j) {
      int col = n0 + (tn << 2) + j;
      size_t idx = (size_t)row * ldc + col;
      const float gate = 1.0f / (1.0f + expf(-Ar[idx] * Wg[col]));
      G[idx] = gate;
      SGr[idx] = accr[i][j] * (1.0f - gate);
      SGi[idx] = acci[i][j] * (1.0f - gate);
    }
  }
}

// ==================== fused forcing + u_out pscan (bf16 in) -> bf16 ub ====================
__global__ __launch_bounds__(256) void pscan_fused_kernel(
    const u16* __restrict__ eig,
    const float* __restrict__ Gv,
    const float* __restrict__ SGr, const float* __restrict__ SGi,
    const float* __restrict__ opfr, const float* __restrict__ opfi,
    const float* __restrict__ opdr, const float* __restrict__ opdi,
    u16* __restrict__ ub) {
  const int g = blockIdx.x * 256 + threadIdx.x;
  if (g >= 4 * 256 * 384) return;
  const int d = g % 384;
  const int pix = (g / 384) & 255;
  const int b = g / (384 * 256);
  float ur = 0.f, ui = 0.f;
  for (int t = 0; t < 12; ++t) {
    const int frame = b * 12 + t;
    const size_t idx = ((size_t)frame * 256 + pix) * 768 + d;
    const int fidx = frame * 384 + d;
    const float G = Gv[fidx];
    const float fr = bf2f(eig[idx]) * G + SGr[fidx];
    const float fi = bf2f(eig[idx + 384]) * G + SGi[fidx];
    const float pr = opfr[fidx], pi = opfi[fidx];
    const float utr = fr * pr - fi * pi;
    const float uti = fr * pi + fi * pr;
    const float ar = opdr[fidx], ai = opdi[fidx];
    const float nr = ar * ur - ai * ui + utr;
    const float ni = ar * ui + ai * ur + uti;
    ub[idx] = f2bf(nr); ub[idx + 384] = f2bf(ni);
    ur = nr; ui = ni;
  }
}

extern "C" void kernel_launch(void* const* d_in, const int* in_sizes, int n_in,
                              void* d_out, int out_size, void* d_ws, size_t ws_size,
                              hipStream_t stream) {
  const float* x        = (const float*)d_in[0];
  const float* dt       = (const float*)d_in[1];
  const float* enc_w    = (const float*)d_in[2];
  const float* enc_b    = (const float*)d_in[3];
  const float* ns_g     = (const float*)d_in[4];
  const float* ns_b     = (const float*)d_in[5];
  const float* cw       = (const float*)d_in[6];
  const float* cb       = (const float*)d_in[7];
  const float* nt_g     = (const float*)d_in[8];
  const float* nt_b     = (const float*)d_in[9];
  const float* E_re     = (const float*)d_in[10];
  const float* E_im     = (const float*)d_in[11];
  const float* Ei_re    = (const float*)d_in[12];
  const float* Ei_im    = (const float*)d_in[13];
  const float* lam_flux = (const float*)d_in[14];
  const float* Ws_re    = (const float*)d_in[15];
  const float* Ws_im    = (const float*)d_in[16];
  const float* Wg       = (const float*)d_in[17];
  const float* nu       = (const float*)d_in[18];
  const float* omega    = (const float*)d_in[19];
  const float* w1_re    = (const float*)d_in[20];
  const float* w1_im    = (const float*)d_in[21];
  const float* w2_re    = (const float*)d_in[22];
  const float* w2_im    = (const float*)d_in[23];
  const float* dec_w    = (const float*)d_in[24];
  const float* dec_b    = (const float*)d_in[25];
  float* out = (float*)d_out;

  const size_t NPF = 12288ull * 768;        // 9,437,184
  const size_t XNP = 48ull * 324 * 768;     // halo-padded plane
  const size_t SM = 48ull * 384;

  float* z    = (float*)d_ws;                // [12288][768] fp32 residual master
  float* eigf = z + NPF;                     // region A (NPF floats)
  float* dff  = eigf + NPF;                  // region B (NPF floats)
  u16* xnp    = (u16*)(dff + NPF);           // halo plane ONLY (borders zeroed once)
  u16* Btc    = xnp + XNP;                   // [768][6912]
  u16* Et     = Btc + 5308416;               // [768][768]
  u16* Eit    = Et + 589824;
  u16* W1t    = Eit + 589824;                // 2 chunks x [1536][768]
  u16* W2t    = W1t + 2359296;               // 2 chunks x [768][1536]
  u16* dwt    = W2t + 2359296;               // [1024][768]
  float* sm   = (float*)(dwt + 786432);
  float* mr    = sm;            float* mi    = mr + SM;
  float* fluxr = mi + SM;       float* fluxi = fluxr + SM;
  float* opdr  = fluxi + SM;    float* opdi  = opdr + SM;
  float* opfr  = opdi + SM;     float* opfi  = opfr + SM;
  float* Gv    = opfi + SM;     float* SGr   = Gv + SM;
  float* SGi   = SGr + SM;

  const size_t need = ((char*)(SGi + SM)) - ((char*)d_ws);
  if (ws_size < need) return;

  // region A: eig_b (1st half) + ub (2nd half); h1b spans full region (disjoint lifetime)
  u16* eig_b = (u16*)eigf;
  u16* ub    = (u16*)eigf + NPF;
  u16* h1b   = (u16*)eigf;
  // region B: df_b (1st half) + {zbuf / xn} (2nd half, disjoint lifetimes)
  u16* df_b  = (u16*)dff;
  u16* zbuf  = (u16*)dff + NPF;
  u16* xn    = (u16*)dff + NPF;

  cast_bf16_kernel<<<(786432 + 255) / 256, 256, 0, stream>>>(dec_w, dwt, 786432);
  hipMemsetAsync(xnp, 0, XNP * sizeof(u16), stream);  // halo borders: zeroed ONCE
  encoder_mfma_kernel<<<dim3(64, 12), 256, 0, stream>>>(x, enc_w, enc_b, z);

  for (int l = 0; l < 4; ++l) {
    const size_t DD = 384ull * 384, DF = 384ull * 1536;
    mega_expand_kernel<<<dim3(48, 48, 7), 256, 0, stream>>>(
        E_re + l * DD, E_im + l * DD, Ei_re + l * DD, Ei_im + l * DD,
        w1_re + l * DF, w1_im + l * DF, w2_re + l * DF, w2_im + l * DF,
        cw + (size_t)l * 768 * 768 * 9, Et, Eit, W1t, W2t, Btc);

    ln_kernel<<<12288, 192, 0, stream>>>(z, ns_g + l * 768, ns_b + l * 768, xnp);
    conv_mfma_kernel<<<dim3(64, 12), 256, 0, stream>>>(xnp, Btc, cb + l * 768, z, zbuf);
    gemm_kernel<64, 6><<<dim3(64, 12), 256, 0, stream>>>(zbuf, Et, 768, 768, nullptr, eig_b, nullptr, nullptr);
    mean_kernel<<<48, 768, 0, stream>>>(eig_b, mr, mi);
    flux_kernel<<<4, 384, 0, stream>>>(dt, lam_flux + l * 384, nu + l * 384, omega + l * 384,
                                       mr, mi, fluxr, fluxi, opdr, opdi, opfr, opfi);
    cgemm_src_kernel<<<dim3(1, 6), 256, 0, stream>>>(
        fluxr, fluxi, 384, Ws_re + l * DD, Ws_im + l * DD, 384,
        Wg + l * 384, Gv, SGr, SGi, 384, 48, 384);
    pscan_fused_kernel<<<1536, 256, 0, stream>>>(eig_b, Gv, SGr, SGi, opfr, opfi, opdr, opdi, ub);
    gemm_kernel<64, 6><<<dim3(64, 12), 256, 0, stream>>>(ub, Eit, 768, 768, nullptr, df_b, nullptr, nullptr);
    ln_bf_kernel<<<12288, 192, 0, stream>>>(df_b, nt_g + l * 768, nt_b + l * 768, xn);
    for (int ch = 0; ch < 2; ++ch) {
      gemm_kernel<64, 1><<<dim3(64, 24), 256, 0, stream>>>(
          xn, W1t + (size_t)ch * 1179648, 768, 1536, nullptr, h1b, nullptr, nullptr);
      if (ch == 0) {
        // z += W2 + df (df-residual fused, bf16 df read)
        gemm_kernel<64, 4><<<dim3(64, 12), 256, 0, stream>>>(
            h1b, W2t, 1536, 768, z, nullptr, nullptr, df_b);
      } else if (l < 3) {
        gemm_kernel<64, 2><<<dim3(64, 12), 256, 0, stream>>>(
            h1b, W2t + 1179648, 1536, 768, z, nullptr, nullptr, nullptr);
      } else {
        // final layer: also emit zbuf for the decoder
        gemm_kernel<64, 5><<<dim3(64, 12), 256, 0, stream>>>(
            h1b, W2t + 1179648, 1536, 768, z, zbuf, nullptr, nullptr);
      }
    }
  }

  gemm_kernel<64, 3><<<dim3(64, 16), 256, 0, stream>>>(zbuf, dwt, 768, 0, out, nullptr, dec_b, nullptr);
}

// Round 4
// 2413.056 us; speedup vs baseline: 1.1632x; 1.0243x over previous
//
#include <hip/hip_runtime.h>
#include <cstddef>
#include <cstdint>

typedef unsigned short u16;
typedef short bf16x8 __attribute__((ext_vector_type(8)));
typedef float f32x4 __attribute__((ext_vector_type(4)));

__device__ __forceinline__ float gelu_tanh(float x) {
  float x3 = x * x * x;
  float t = tanhf(0.7978845608028654f * (x + 0.044715f * x3));
  return 0.5f * x * (1.0f + t);
}
__device__ __forceinline__ float softplus_f(float x) {
  return (x > 20.0f) ? x : log1pf(expf(x));
}
__device__ __forceinline__ u16 f2bf(float f) {
  uint32_t u = __float_as_uint(f);
  uint32_t r = (u + 0x7fffu + ((u >> 16) & 1u)) >> 16;
  return (u16)r;
}
__device__ __forceinline__ float bf2f(u16 v) {
  return __uint_as_float(((uint32_t)v) << 16);
}

// async global->LDS, 16B/lane; LDS dest = wave-uniform base + lane*16, global src per-lane
__device__ __forceinline__ void gload16(const u16* g, u16* l) {
  __builtin_amdgcn_global_load_lds(
      (const __attribute__((address_space(1))) void*)g,
      (__attribute__((address_space(3))) void*)l, 16, 0, 0);
}

// ==================== unified MFMA GEMM, 192x64 tile, two-panel BK=64 ====================
// MODE 0: Cf = v              MODE 1: Cb = bf16(gelu(v))
// MODE 2: Cf += v             MODE 3: decoder scatter out = v + bias
// MODE 4: Cf += v + bf2f(Db)  MODE 5: Cf += v; Cb = bf16(Cf)
// MODE 6: Cb = bf16(v)        MODE 7: Cb = bf16(v) + fused pixel-mean atomics -> mrp/mip
template <int TN, int MODE>
__global__ __launch_bounds__(256) void gemm_kernel(
    const u16* __restrict__ A, const u16* __restrict__ Bt, int K, int ldc,
    float* __restrict__ Cf, u16* __restrict__ Cb,
    const float* __restrict__ bias, const u16* __restrict__ Db,
    float* __restrict__ mrp, float* __restrict__ mip) {
  static_assert(TN == 64, "192x64 tile only");
  __shared__ u16 As[2][192 * 32];
  __shared__ u16 Bs[2][64 * 32];
  const int m0 = blockIdx.x * 192, n0 = blockIdx.y * 64;
  const int tid = threadIdx.x;
  const int lane = tid & 63, w = tid >> 6;
  const int lane15 = lane & 15, quad = lane >> 4;
  const int r0 = lane >> 2, e0 = (lane & 3) * 8;

  const u16* ag0 = A + (size_t)(m0 + w * 48 + r0) * K + e0;
  const u16* ag1 = ag0 + (size_t)16 * K;
  const u16* ag2 = ag0 + (size_t)32 * K;
  const u16* bg0 = Bt + (size_t)(n0 + w * 16 + r0) * K + e0;

  f32x4 acc[3][4] = {};
  const int abase = (w * 48 + lane15) * 32 + quad * 8;
  const int bbase = lane15 * 32 + quad * 8;

  for (int k0 = 0; k0 < K; k0 += 64) {
#pragma unroll
    for (int p = 0; p < 2; ++p) {
      const int kk = k0 + 32 * p;
      gload16(ag0 + kk, &As[p][(w * 48) * 32]);
      gload16(ag1 + kk, &As[p][(w * 48 + 16) * 32]);
      gload16(ag2 + kk, &As[p][(w * 48 + 32) * 32]);
      gload16(bg0 + kk, &Bs[p][(w * 16) * 32]);
    }
    __syncthreads();
#pragma unroll
    for (int p = 0; p < 2; ++p) {
      bf16x8 af[3], bf[4];
#pragma unroll
      for (int i = 0; i < 3; ++i) af[i] = *(const bf16x8*)&As[p][abase + i * 16 * 32];
#pragma unroll
      for (int j = 0; j < 4; ++j) bf[j] = *(const bf16x8*)&Bs[p][bbase + j * 16 * 32];
#pragma unroll
      for (int i = 0; i < 3; ++i)
#pragma unroll
        for (int j = 0; j < 4; ++j)
          acc[i][j] = __builtin_amdgcn_mfma_f32_16x16x32_bf16(af[i], bf[j], acc[i][j], 0, 0, 0);
    }
    __syncthreads();
  }

  const int mw = m0 + w * 48;
#pragma unroll
  for (int i = 0; i < 3; ++i) {
#pragma unroll
    for (int j = 0; j < 4; ++j) {
      const int col = n0 + j * 16 + lane15;
#pragma unroll
      for (int r = 0; r < 4; ++r) {
        const int row = mw + i * 16 + quad * 4 + r;
        const float v = acc[i][j][r];
        const size_t idx = (size_t)row * ldc + col;
        if (MODE == 0) {
          Cf[idx] = v;
        } else if (MODE == 1) {
          Cb[idx] = f2bf(gelu_tanh(v));
        } else if (MODE == 2) {
          Cf[idx] += v;
        } else if (MODE == 3) {
          const int frame = row >> 8, pix = row & 255;
          const int hp = pix >> 4, wp = pix & 15;
          const int co = col >> 8, p1 = (col >> 4) & 15, p2 = col & 15;
          Cf[(((size_t)frame * 4 + co) * 256 + hp * 16 + p1) * 256 + wp * 16 + p2] = v + bias[col];
        } else if (MODE == 4) {
          Cf[idx] += v + bf2f(Db[idx]);
        } else if (MODE == 5) {
          const float nz = Cf[idx] + v;
          Cf[idx] = nz;
          Cb[idx] = f2bf(nz);
        } else if (MODE == 6 || MODE == 7) {
          Cb[idx] = f2bf(v);
        }
      }
      if (MODE == 7) {
        // fused pixel-mean: sum 4 rows (one 16-aligned i-group -> frame is
        // quad-uniform), reduce across the 4 quads, one atomic from quad 0.
        float sv = acc[i][j][0] + acc[i][j][1] + acc[i][j][2] + acc[i][j][3];
        sv += __shfl_xor(sv, 16);
        sv += __shfl_xor(sv, 32);
        if (quad == 0) {
          const int fr = (mw + i * 16) >> 8;
          float* tgt = (col < 384) ? (mrp + fr * 384 + col)
                                   : (mip + fr * 384 + (col - 384));
          atomicAdd(tgt, sv * (1.0f / 256.0f));
        }
      }
    }
  }
}

// ==================== conv3x3 implicit-GEMM, 192x64 tile, dx-fused ====================
__global__ __launch_bounds__(256) void conv_mfma_kernel(
    const u16* __restrict__ xnp, const u16* __restrict__ Btc,
    const float* __restrict__ cbias,
    float* __restrict__ z, u16* __restrict__ zb) {
  __shared__ u16 As[2][4 * 54 * 32];      // [panel][wave][halo-pos 0..53][32K]
  __shared__ u16 Bs[2][3 * 64 * 32];      // [panel][dx][row 0..63][32K]
  const int m0 = blockIdx.x * 192, n0 = blockIdx.y * 64;
  const int tid = threadIdx.x;
  const int lane = tid & 63, w = tid >> 6;
  const int lane15 = lane & 15, quad = lane >> 4;
  const int r0 = lane >> 2, e0 = (lane & 3) * 8;

  const int rowA0 = m0 + w * 48;               // wave base row (multiple of 48)
  const int q = (rowA0 >> 4) & 15;             // starting pixel-row within frame
  const bool fast = (q <= 13);                 // all 3 pixel-rows in one frame
  const long long cbase = ((long long)(rowA0 >> 8) * 324 + q * 18) * 768;

  int fhp[3];
#pragma unroll
  for (int s = 0; s < 3; ++s) {
    const int rA = rowA0 + s * 16;
    fhp[s] = (rA >> 8) * 324 + ((rA & 255) >> 4) * 18;
  }
  const u16* bgt = Btc + (size_t)(n0 + w * 16 + r0) * 6912 + e0;

  f32x4 acc[3][4] = {};
  const int aseg = w * 54 * 32;  // wave's A base within a panel

  for (int dy = 0; dy < 3; ++dy) {
    const u16* afast = xnp + cbase + (size_t)dy * (18 * 768) + (size_t)r0 * 768 + e0;
    const u16* asrc[3];
#pragma unroll
    for (int s = 0; s < 3; ++s)
      asrc[s] = xnp + ((size_t)(fhp[s] + dy * 18 + r0)) * 768 + e0;
    const u16* bsrc = bgt + dy * 3 * 768;

    for (int kc = 0; kc < 768; kc += 64) {
#pragma unroll
      for (int p = 0; p < 2; ++p) {
        const int kk = kc + 32 * p;
        if (fast) {
          gload16(afast + kk, &As[p][aseg]);
          gload16(afast + kk + 16 * 768, &As[p][aseg + 16 * 32]);
          gload16(afast + kk + 32 * 768, &As[p][aseg + 32 * 32]);
          gload16(afast + kk + 38 * 768, &As[p][aseg + 38 * 32]);
        } else {
#pragma unroll
          for (int s = 0; s < 3; ++s) {
            gload16(asrc[s] + kk, &As[p][aseg + s * 18 * 32]);
            gload16(asrc[s] + kk + 2 * 768, &As[p][aseg + s * 18 * 32 + 2 * 32]);
          }
        }
#pragma unroll
        for (int dx = 0; dx < 3; ++dx)
          gload16(bsrc + dx * 768 + kk, &Bs[p][(dx * 64 + w * 16) * 32]);
      }
      __syncthreads();
#pragma unroll
      for (int p = 0; p < 2; ++p) {
#pragma unroll
        for (int dx = 0; dx < 3; ++dx) {
          bf16x8 af[3], bf[4];
#pragma unroll
          for (int i = 0; i < 3; ++i)
            af[i] = *(const bf16x8*)&As[p][aseg + (i * 18 + lane15 + dx) * 32 + quad * 8];
#pragma unroll
          for (int j = 0; j < 4; ++j)
            bf[j] = *(const bf16x8*)&Bs[p][(dx * 64 + j * 16 + lane15) * 32 + quad * 8];
#pragma unroll
          for (int i = 0; i < 3; ++i)
#pragma unroll
            for (int j = 0; j < 4; ++j)
              acc[i][j] = __builtin_amdgcn_mfma_f32_16x16x32_bf16(af[i], bf[j], acc[i][j], 0, 0, 0);
        }
      }
      __syncthreads();
    }
  }

  const int mw = m0 + w * 48;
#pragma unroll
  for (int i = 0; i < 3; ++i) {
#pragma unroll
    for (int j = 0; j < 4; ++j) {
      const int col = n0 + j * 16 + lane15;
      const float bv = cbias[col];
#pragma unroll
      for (int r = 0; r < 4; ++r) {
        const int row = mw + i * 16 + quad * 4 + r;
        const size_t idx = (size_t)row * 768 + col;
        const float nz = z[idx] + acc[i][j][r] + bv;
        z[idx] = nz;
        zb[idx] = f2bf(nz);
      }
    }
  }
}

// ==================== encoder: patch-embed MFMA, 192x64 tile (runs once) ====================
__global__ __launch_bounds__(256) void encoder_mfma_kernel(
    const float* __restrict__ x, const float* __restrict__ ew,
    const float* __restrict__ eb, float* __restrict__ z) {
  __shared__ u16 As[192 * 32];
  __shared__ u16 Bs[64 * 32];
  const int m0 = blockIdx.x * 192, n0 = blockIdx.y * 64;
  const int tid = threadIdx.x;
  const int lane = tid & 63, w = tid >> 6;
  const int lane15 = lane & 15, quad = lane >> 4;

  f32x4 acc[3][4] = {};
  const int abase = (w * 48 + lane15) * 32 + quad * 8;
  const int bbase = lane15 * 32 + quad * 8;

  for (int k0 = 0; k0 < 1024; k0 += 32) {
    __syncthreads();
#pragma unroll
    for (int pass = 0; pass < 3; ++pass) {
      const int id = tid + pass * 256;  // 0..767
      const int row = id >> 2, kc8 = (id & 3) * 8;
      const int arow = m0 + row;
      const int frame = arow >> 8, pix = arow & 255, hh = pix >> 4, ww = pix & 15;
      const int gk = k0 + kc8;
      const int c = gk >> 8, ph = (gk >> 4) & 15, pw = gk & 15;
      const float* ax = x + (((size_t)(frame * 4 + c) * 256 + hh * 16 + ph) * 256 + ww * 16 + pw);
      const float4 v0 = *(const float4*)ax;
      const float4 v1 = *(const float4*)(ax + 4);
      u16 t8[8];
      t8[0] = f2bf(v0.x); t8[1] = f2bf(v0.y); t8[2] = f2bf(v0.z); t8[3] = f2bf(v0.w);
      t8[4] = f2bf(v1.x); t8[5] = f2bf(v1.y); t8[6] = f2bf(v1.z); t8[7] = f2bf(v1.w);
      *(uint4*)&As[row * 32 + kc8] = *(uint4*)t8;
    }
    {
      const int row = tid >> 2, kc8 = (tid & 3) * 8;
      const float* bx = ew + (size_t)(n0 + row) * 1024 + k0 + kc8;
      const float4 v0 = *(const float4*)bx;
      const float4 v1 = *(const float4*)(bx + 4);
      u16 t8[8];
      t8[0] = f2bf(v0.x); t8[1] = f2bf(v0.y); t8[2] = f2bf(v0.z); t8[3] = f2bf(v0.w);
      t8[4] = f2bf(v1.x); t8[5] = f2bf(v1.y); t8[6] = f2bf(v1.z); t8[7] = f2bf(v1.w);
      *(uint4*)&Bs[row * 32 + kc8] = *(uint4*)t8;
    }
    __syncthreads();
    bf16x8 af[3], bfv[4];
#pragma unroll
    for (int i = 0; i < 3; ++i) af[i] = *(const bf16x8*)&As[abase + i * 16 * 32];
#pragma unroll
    for (int j = 0; j < 4; ++j) bfv[j] = *(const bf16x8*)&Bs[bbase + j * 16 * 32];
#pragma unroll
    for (int i = 0; i < 3; ++i)
#pragma unroll
      for (int j = 0; j < 4; ++j)
        acc[i][j] = __builtin_amdgcn_mfma_f32_16x16x32_bf16(af[i], bfv[j], acc[i][j], 0, 0, 0);
  }

  const int mw = m0 + w * 48;
#pragma unroll
  for (int i = 0; i < 3; ++i)
#pragma unroll
    for (int j = 0; j < 4; ++j) {
      const int col = n0 + j * 16 + lane15;
      const float bv = eb[col];
#pragma unroll
      for (int r = 0; r < 4; ++r) {
        const int row = mw + i * 16 + quad * 4 + r;
        z[(size_t)row * 768 + col] = acc[i][j][r] + bv;
      }
    }
}

// ==================== mega weight-prep: all 6 expands + cw reorder in ONE launch ====================
__global__ __launch_bounds__(256) void mega_expand_kernel(
    const float* __restrict__ E_re, const float* __restrict__ E_im,
    const float* __restrict__ Ei_re, const float* __restrict__ Ei_im,
    const float* __restrict__ w1_re, const float* __restrict__ w1_im,
    const float* __restrict__ w2_re, const float* __restrict__ w2_im,
    const float* __restrict__ cwl,
    u16* __restrict__ Et, u16* __restrict__ Eit,
    u16* __restrict__ W1t, u16* __restrict__ W2t, u16* __restrict__ Btc) {
  __shared__ float shbuf[6912];
  const int zz = blockIdx.z;

  if (zz == 6) {
    const int o = blockIdx.y * 48 + blockIdx.x;
    if (o >= 768) return;
    const float* src = cwl + (size_t)o * 6912;
    for (int i = threadIdx.x; i < 6912; i += 256) shbuf[i] = src[i];
    __syncthreads();
    u16* dst = Btc + (size_t)o * 6912;
    for (int i = threadIdx.x; i < 6912; i += 256) {
      const int tap = i / 768, cc = i - tap * 768;
      dst[i] = f2bf(shbuf[cc * 9 + tap]);
    }
    return;
  }

  const float *Wre, *Wim;
  int ldw, Kc, Nc, gx, gy;
  u16* Wt;
  const size_t DF = 384ull * 1536;
  switch (zz) {
    case 0:  Wre = E_re;  Wim = E_im;  ldw = 384;  Kc = 384; Nc = 384; Wt = Et;  gx = 24; gy = 24; break;
    case 1:  Wre = Ei_re; Wim = Ei_im; ldw = 384;  Kc = 384; Nc = 384; Wt = Eit; gx = 24; gy = 24; break;
    case 2:  Wre = w1_re; Wim = w1_im; ldw = 1536; Kc = 384; Nc = 768; Wt = W1t; gx = 24; gy = 48; break;
    case 3:  Wre = w1_re + 768; Wim = w1_im + 768; ldw = 1536; Kc = 384; Nc = 768;
             Wt = W1t + 1179648; gx = 24; gy = 48; break;
    case 4:  Wre = w2_re; Wim = w2_im; ldw = 384;  Kc = 768; Nc = 384; Wt = W2t; gx = 48; gy = 24; break;
    default: Wre = w2_re + DF / 2; Wim = w2_im + DF / 2; ldw = 384; Kc = 768; Nc = 384;
             Wt = W2t + 1179648; gx = 48; gy = 24; break;
  }
  if ((int)blockIdx.x >= gx || (int)blockIdx.y >= gy) return;

  float (*tile)[33] = (float(*)[33])shbuf;
  const int k0 = blockIdx.x * 32, n0 = blockIdx.y * 32;
  const bool khi = k0 >= Kc, nhi = n0 >= Nc;
  const float* src = (khi != nhi) ? Wim : Wre;
  const float sgn = (!nhi && khi) ? -1.0f : 1.0f;
  const int sk = k0 - (khi ? Kc : 0), sn = n0 - (nhi ? Nc : 0);
  const int c = threadIdx.x & 31, r8 = threadIdx.x >> 5;
  for (int r = r8; r < 32; r += 8)
    tile[r][c] = src[(size_t)(sk + r) * ldw + sn + c];
  __syncthreads();
  const int twoK = 2 * Kc;
  for (int r = r8; r < 32; r += 8)
    Wt[(size_t)(n0 + r) * twoK + k0 + c] = f2bf(sgn * tile[c][r]);
}

__global__ __launch_bounds__(256) void cast_bf16_kernel(
    const float* __restrict__ in, u16* __restrict__ out, int n) {
  const int g = blockIdx.x * 256 + threadIdx.x;
  if (g < n) out[g] = f2bf(in[g]);
}

// ==================== LayerNorm fp32-in (halo writer), wave-per-row ====================
// 64 lanes x 12 elems, butterfly shfl reduce, no LDS/barriers; 4 rows/block.
__global__ __launch_bounds__(256) void ln_kernel(
    const float* __restrict__ in, const float* __restrict__ g,
    const float* __restrict__ b, u16* __restrict__ out) {
  const int row = blockIdx.x * 4 + (threadIdx.x >> 6);
  const int lane = threadIdx.x & 63;
  const float* ip = in + (size_t)row * 768 + lane * 4;
  float4 v[3];
  float s = 0.f, q = 0.f;
#pragma unroll
  for (int k = 0; k < 3; ++k) {
    v[k] = *(const float4*)(ip + k * 256);
    s += v[k].x + v[k].y + v[k].z + v[k].w;
    q += v[k].x * v[k].x + v[k].y * v[k].y + v[k].z * v[k].z + v[k].w * v[k].w;
  }
#pragma unroll
  for (int off = 32; off > 0; off >>= 1) {
    s += __shfl_xor(s, off);
    q += __shfl_xor(q, off);
  }
  const float mean = s * (1.0f / 768.0f);
  const float inv = rsqrtf(q * (1.0f / 768.0f) - mean * mean + 1e-5f);
  const int f = row >> 8, pp = row & 255, h = pp >> 4, ww = pp & 15;
  const size_t base = ((size_t)f * 324 + (h + 1) * 18 + ww + 1) * 768 + lane * 4;
#pragma unroll
  for (int k = 0; k < 3; ++k) {
    const float4 gv = *(const float4*)(g + k * 256 + lane * 4);
    const float4 bv = *(const float4*)(b + k * 256 + lane * 4);
    u16 p[4];
    p[0] = f2bf((v[k].x - mean) * inv * gv.x + bv.x);
    p[1] = f2bf((v[k].y - mean) * inv * gv.y + bv.y);
    p[2] = f2bf((v[k].z - mean) * inv * gv.z + bv.z);
    p[3] = f2bf((v[k].w - mean) * inv * gv.w + bv.w);
    *(uint2*)(out + base + k * 256) = *(uint2*)p;
  }
}

// ==================== LayerNorm bf16-in (flat writer), wave-per-row ====================
__global__ __launch_bounds__(256) void ln_bf_kernel(
    const u16* __restrict__ in, const float* __restrict__ g,
    const float* __restrict__ b, u16* __restrict__ out) {
  const int row = blockIdx.x * 4 + (threadIdx.x >> 6);
  const int lane = threadIdx.x & 63;
  const u16* ip = in + (size_t)row * 768 + lane * 4;
  float v[3][4];
  float s = 0.f, q = 0.f;
#pragma unroll
  for (int k = 0; k < 3; ++k) {
    const uint2 raw = *(const uint2*)(ip + k * 256);
    const u16* rp = (const u16*)&raw;
    v[k][0] = bf2f(rp[0]); v[k][1] = bf2f(rp[1]);
    v[k][2] = bf2f(rp[2]); v[k][3] = bf2f(rp[3]);
    s += v[k][0] + v[k][1] + v[k][2] + v[k][3];
    q += v[k][0] * v[k][0] + v[k][1] * v[k][1] + v[k][2] * v[k][2] + v[k][3] * v[k][3];
  }
#pragma unroll
  for (int off = 32; off > 0; off >>= 1) {
    s += __shfl_xor(s, off);
    q += __shfl_xor(q, off);
  }
  const float mean = s * (1.0f / 768.0f);
  const float inv = rsqrtf(q * (1.0f / 768.0f) - mean * mean + 1e-5f);
  u16* op = out + (size_t)row * 768 + lane * 4;
#pragma unroll
  for (int k = 0; k < 3; ++k) {
    const float4 gv = *(const float4*)(g + k * 256 + lane * 4);
    const float4 bv = *(const float4*)(b + k * 256 + lane * 4);
    u16 p[4];
    p[0] = f2bf((v[k][0] - mean) * inv * gv.x + bv.x);
    p[1] = f2bf((v[k][1] - mean) * inv * gv.y + bv.y);
    p[2] = f2bf((v[k][2] - mean) * inv * gv.z + bv.z);
    p[3] = f2bf((v[k][3] - mean) * inv * gv.w + bv.w);
    *(uint2*)(op + k * 256) = *(uint2*)p;
  }
}

// ==================== flux scan + operator precompute ====================
__global__ __launch_bounds__(384) void flux_kernel(
    const float* __restrict__ dt, const float* __restrict__ lamf,
    const float* __restrict__ nu, const float* __restrict__ omega,
    const float* __restrict__ mr, const float* __restrict__ mi,
    float* __restrict__ fluxr, float* __restrict__ fluxi,
    float* __restrict__ opdr, float* __restrict__ opdi,
    float* __restrict__ opfr, float* __restrict__ opfi) {
  const int b = blockIdx.x;
  const int d = threadIdx.x;
  const float sp = softplus_f(lamf[d]);
  float lre = -softplus_f(nu[d]);
  lre = fmaxf(lre, -5.0f);
  const float lim = omega[d];
  const float den = lre * lre + lim * lim;
  float fr = 0.f, fi = 0.f;
  for (int t = 0; t < 12; ++t) {
    const float dtv = dt[b * 12 + t];
    const int idx = (b * 12 + t) * 384 + d;
    const float A = expf(-sp * dtv);
    fr = A * fr + mr[idx] * dtv;
    fi = A * fi + mi[idx] * dtv;
    fluxr[idx] = fr; fluxi[idx] = fi;
    const float ed = expf(lre * dtv);
    const float odr = ed * cosf(lim * dtv);
    const float odi = ed * sinf(lim * dtv);
    opdr[idx] = odr; opdi[idx] = odi;
    const float nr_ = odr - 1.0f, ni_ = odi;
    opfr[idx] = (nr_ * lre + ni_ * lim) / den;
    opfi[idx] = (ni_ * lre - nr_ * lim) / den;
  }
}

// ==================== small fp32 complex GEMM + gate-product epilogue ====================
#define SBM 64
#define SBN 64
#define SBK 32
__global__ __launch_bounds__(256) void cgemm_src_kernel(
    const float* __restrict__ Ar, const float* __restrict__ Ai, int lda,
    const float* __restrict__ Wr, const float* __restrict__ Wi, int ldw,
    const float* __restrict__ Wg,
    float* __restrict__ G, float* __restrict__ SGr, float* __restrict__ SGi,
    int ldc, int M, int K) {
  __shared__ float Asr[SBK][SBM], Asi[SBK][SBM];
  __shared__ float Wsr[SBK][SBN], Wsi[SBK][SBN];
  const int m0 = blockIdx.x * SBM;
  const int n0 = blockIdx.y * SBN;
  const int tid = threadIdx.x;
  const int tn = tid & 15, tm = tid >> 4;
  float accr[4][4] = {}, acci[4][4] = {};
  for (int k0 = 0; k0 < K; k0 += SBK) {
    for (int s = tid; s < 512; s += 256) {
      {
        int r = s >> 3, kk = (s & 7) << 2;
        int row = m0 + r;
        float4 vr = {0.f, 0.f, 0.f, 0.f}, vi = {0.f, 0.f, 0.f, 0.f};
        if (row < M) {
          vr = *(const float4*)(Ar + (size_t)row * lda + k0 + kk);
          vi = *(const float4*)(Ai + (size_t)row * lda + k0 + kk);
        }
        Asr[kk + 0][r] = vr.x; Asr[kk + 1][r] = vr.y; Asr[kk + 2][r] = vr.z; Asr[kk + 3][r] = vr.w;
        Asi[kk + 0][r] = vi.x; Asi[kk + 1][r] = vi.y; Asi[kk + 2][r] = vi.z; Asi[kk + 3][r] = vi.w;
      }
      {
        int wr_ = s >> 4, wc = (s & 15) << 2;
        *(float4*)&Wsr[wr_][wc] = *(const float4*)(Wr + (size_t)(k0 + wr_) * ldw + n0 + wc);
        *(float4*)&Wsi[wr_][wc] = *(const float4*)(Wi + (size_t)(k0 + wr_) * ldw + n0 + wc);
      }
    }
    __syncthreads();
#pragma unroll
    for (int kk = 0; kk < SBK; ++kk) {
      float4 ar4 = *(const float4*)&Asr[kk][tm << 2];
      float4 ai4 = *(const float4*)&Asi[kk][tm << 2];
      float4 wr4 = *(const float4*)&Wsr[kk][tn << 2];
      float4 wi4 = *(const float4*)&Wsi[kk][tn << 2];
      float ar[4] = {ar4.x, ar4.y, ar4.z, ar4.w};
      float ai[4] = {ai4.x, ai4.y, ai4.z, ai4.w};
      float wr[4] = {wr4.x, wr4.y, wr4.z, wr4.w};
      float wi[4] = {wi4.x, wi4.y, wi4.z, wi4.w};
#pragma unroll
      for (int i = 0; i < 4; ++i)
#pragma unroll
        for (int j = 0; j < 4; ++j) {
          accr[i][j] = fmaf(ar[i], wr[j], accr[i][j]);
          accr[i][j] = fmaf(-ai[i], wi[j], accr[i][j]);
          acci[i][j] = fmaf(ar[i], wi[j], acci[i][j]);
          acci[i][j] = fmaf(ai[i], wr[j], acci[i][j]);
        }
    }
    __syncthreads();
  }
#pragma unroll
  for (int i = 0; i < 4; ++i) {
    int row = m0 + (tm << 2) + i;
    if (row >= M) continue;
#pragma unroll
    for (int j = 0; j < 4; ++j) {
      int col = n0 + (tn << 2) + j;
      size_t idx = (size_t)row * ldc + col;
      const float gate = 1.0f / (1.0f + expf(-Ar[idx] * Wg[col]));
      G[idx] = gate;
      SGr[idx] = accr[i][j] * (1.0f - gate);
      SGi[idx] = acci[i][j] * (1.0f - gate);
    }
  }
}

// ==================== fused forcing + u_out pscan (bf16 in) -> bf16 ub ====================
__global__ __launch_bounds__(256) void pscan_fused_kernel(
    const u16* __restrict__ eig,
    const float* __restrict__ Gv,
    const float* __restrict__ SGr, const float* __restrict__ SGi,
    const float* __restrict__ opfr, const float* __restrict__ opfi,
    const float* __restrict__ opdr, const float* __restrict__ opdi,
    u16* __restrict__ ub) {
  const int g = blockIdx.x * 256 + threadIdx.x;
  if (g >= 4 * 256 * 384) return;
  const int d = g % 384;
  const int pix = (g / 384) & 255;
  const int b = g / (384 * 256);
  float ur = 0.f, ui = 0.f;
  for (int t = 0; t < 12; ++t) {
    const int frame = b * 12 + t;
    const size_t idx = ((size_t)frame * 256 + pix) * 768 + d;
    const int fidx = frame * 384 + d;
    const float G = Gv[fidx];
    const float fr = bf2f(eig[idx]) * G + SGr[fidx];
    const float fi = bf2f(eig[idx + 384]) * G + SGi[fidx];
    const float pr = opfr[fidx], pi = opfi[fidx];
    const float utr = fr * pr - fi * pi;
    const float uti = fr * pi + fi * pr;
    const float ar = opdr[fidx], ai = opdi[fidx];
    const float nr = ar * ur - ai * ui + utr;
    const float ni = ar * ui + ai * ur + uti;
    ub[idx] = f2bf(nr); ub[idx + 384] = f2bf(ni);
    ur = nr; ui = ni;
  }
}

extern "C" void kernel_launch(void* const* d_in, const int* in_sizes, int n_in,
                              void* d_out, int out_size, void* d_ws, size_t ws_size,
                              hipStream_t stream) {
  const float* x        = (const float*)d_in[0];
  const float* dt       = (const float*)d_in[1];
  const float* enc_w    = (const float*)d_in[2];
  const float* enc_b    = (const float*)d_in[3];
  const float* ns_g     = (const float*)d_in[4];
  const float* ns_b     = (const float*)d_in[5];
  const float* cw       = (const float*)d_in[6];
  const float* cb       = (const float*)d_in[7];
  const float* nt_g     = (const float*)d_in[8];
  const float* nt_b     = (const float*)d_in[9];
  const float* E_re     = (const float*)d_in[10];
  const float* E_im     = (const float*)d_in[11];
  const float* Ei_re    = (const float*)d_in[12];
  const float* Ei_im    = (const float*)d_in[13];
  const float* lam_flux = (const float*)d_in[14];
  const float* Ws_re    = (const float*)d_in[15];
  const float* Ws_im    = (const float*)d_in[16];
  const float* Wg       = (const float*)d_in[17];
  const float* nu       = (const float*)d_in[18];
  const float* omega    = (const float*)d_in[19];
  const float* w1_re    = (const float*)d_in[20];
  const float* w1_im    = (const float*)d_in[21];
  const float* w2_re    = (const float*)d_in[22];
  const float* w2_im    = (const float*)d_in[23];
  const float* dec_w    = (const float*)d_in[24];
  const float* dec_b    = (const float*)d_in[25];
  float* out = (float*)d_out;

  const size_t NPF = 12288ull * 768;        // 9,437,184
  const size_t XNP = 48ull * 324 * 768;     // halo-padded plane
  const size_t SM = 48ull * 384;

  float* z    = (float*)d_ws;                // [12288][768] fp32 residual master
  float* eigf = z + NPF;                     // region A (NPF floats)
  float* dff  = eigf + NPF;                  // region B (NPF floats)
  u16* xnp    = (u16*)(dff + NPF);           // halo plane ONLY (borders zeroed once)
  u16* Btc    = xnp + XNP;                   // [768][6912]
  u16* Et     = Btc + 5308416;               // [768][768]
  u16* Eit    = Et + 589824;
  u16* W1t    = Eit + 589824;                // 2 chunks x [1536][768]
  u16* W2t    = W1t + 2359296;               // 2 chunks x [768][1536]
  u16* dwt    = W2t + 2359296;               // [1024][768]
  float* sm   = (float*)(dwt + 786432);
  float* mr    = sm;            float* mi    = mr + SM;
  float* fluxr = mi + SM;       float* fluxi = fluxr + SM;
  float* opdr  = fluxi + SM;    float* opdi  = opdr + SM;
  float* opfr  = opdi + SM;     float* opfi  = opfr + SM;
  float* Gv    = opfi + SM;     float* SGr   = Gv + SM;
  float* SGi   = SGr + SM;

  const size_t need = ((char*)(SGi + SM)) - ((char*)d_ws);
  if (ws_size < need) return;

  // region A: eig_b (1st half) + ub (2nd half); h1b spans full region (disjoint lifetime)
  u16* eig_b = (u16*)eigf;
  u16* ub    = (u16*)eigf + NPF;
  u16* h1b   = (u16*)eigf;
  // region B: df_b (1st half) + {zbuf / xn} (2nd half, disjoint lifetimes)
  u16* df_b  = (u16*)dff;
  u16* zbuf  = (u16*)dff + NPF;
  u16* xn    = (u16*)dff + NPF;

  cast_bf16_kernel<<<(786432 + 255) / 256, 256, 0, stream>>>(dec_w, dwt, 786432);
  hipMemsetAsync(xnp, 0, XNP * sizeof(u16), stream);  // halo borders: zeroed ONCE
  encoder_mfma_kernel<<<dim3(64, 12), 256, 0, stream>>>(x, enc_w, enc_b, z);

  for (int l = 0; l < 4; ++l) {
    const size_t DD = 384ull * 384, DF = 384ull * 1536;
    mega_expand_kernel<<<dim3(48, 48, 7), 256, 0, stream>>>(
        E_re + l * DD, E_im + l * DD, Ei_re + l * DD, Ei_im + l * DD,
        w1_re + l * DF, w1_im + l * DF, w2_re + l * DF, w2_im + l * DF,
        cw + (size_t)l * 768 * 768 * 9, Et, Eit, W1t, W2t, Btc);

    ln_kernel<<<3072, 256, 0, stream>>>(z, ns_g + l * 768, ns_b + l * 768, xnp);
    conv_mfma_kernel<<<dim3(64, 12), 256, 0, stream>>>(xnp, Btc, cb + l * 768, z, zbuf);
    hipMemsetAsync(mr, 0, 2 * SM * sizeof(float), stream);  // zero mr+mi (contiguous)
    gemm_kernel<64, 7><<<dim3(64, 12), 256, 0, stream>>>(
        zbuf, Et, 768, 768, nullptr, eig_b, nullptr, nullptr, mr, mi);
    flux_kernel<<<4, 384, 0, stream>>>(dt, lam_flux + l * 384, nu + l * 384, omega + l * 384,
                                       mr, mi, fluxr, fluxi, opdr, opdi, opfr, opfi);
    cgemm_src_kernel<<<dim3(1, 6), 256, 0, stream>>>(
        fluxr, fluxi, 384, Ws_re + l * DD, Ws_im + l * DD, 384,
        Wg + l * 384, Gv, SGr, SGi, 384, 48, 384);
    pscan_fused_kernel<<<1536, 256, 0, stream>>>(eig_b, Gv, SGr, SGi, opfr, opfi, opdr, opdi, ub);
    gemm_kernel<64, 6><<<dim3(64, 12), 256, 0, stream>>>(
        ub, Eit, 768, 768, nullptr, df_b, nullptr, nullptr, nullptr, nullptr);
    ln_bf_kernel<<<3072, 256, 0, stream>>>(df_b, nt_g + l * 768, nt_b + l * 768, xn);
    for (int ch = 0; ch < 2; ++ch) {
      gemm_kernel<64, 1><<<dim3(64, 24), 256, 0, stream>>>(
          xn, W1t + (size_t)ch * 1179648, 768, 1536, nullptr, h1b, nullptr, nullptr, nullptr, nullptr);
      if (ch == 0) {
        // z += W2 + df (df-residual fused, bf16 df read)
        gemm_kernel<64, 4><<<dim3(64, 12), 256, 0, stream>>>(
            h1b, W2t, 1536, 768, z, nullptr, nullptr, df_b, nullptr, nullptr);
      } else if (l < 3) {
        gemm_kernel<64, 2><<<dim3(64, 12), 256, 0, stream>>>(
            h1b, W2t + 1179648, 1536, 768, z, nullptr, nullptr, nullptr, nullptr, nullptr);
      } else {
        // final layer: also emit zbuf for the decoder
        gemm_kernel<64, 5><<<dim3(64, 12), 256, 0, stream>>>(
            h1b, W2t + 1179648, 1536, 768, z, zbuf, nullptr, nullptr, nullptr, nullptr);
      }
    }
  }

  gemm_kernel<64, 3><<<dim3(64, 16), 256, 0, stream>>>(
      zbuf, dwt, 768, 0, out, nullptr, dec_b, nullptr, nullptr, nullptr);
}